// Round 13
// baseline (284.180 us; speedup 1.0000x reference)
//
#include <hip/hip_runtime.h>
#include <math.h>

typedef float    f32x4 __attribute__((ext_vector_type(4)));
typedef unsigned u32x4 __attribute__((ext_vector_type(4)));

// ws layout (uint32 words), total 925376 words = 3.70 MB (r11/r12-proven):
//   [0      .. 16384)  HBIG   : G1 gray hist (main) / fallback window hist
//   [16384  .. 20480)  H12    : FALLBACK 12-bit histogram (fkA)
//   [20480  .. 20544)  H64    : fallback 64-sub-bin hist
//   [20544  .. 24640)  SH12   : sample hist12
//   [24640  .. 24840)  SHSUB  : sample sub-bin hist (192 used)
//   [24840  .. 24864)  CTRL
//   [24864  .. 25376)  FINE
//   [25376  .. +2*GRAY_CAP)   : phase 1 (pre-kA): sample bits (n/64 words)
//                               phase 2 (main): gray idx, then gray eb
//                               phase 2 (fallback): candidate x floats
#define HBIG_OFF   0u
#define H12_OFF    16384u
#define H64_OFF    20480u
#define SH12_OFF   20544u
#define SHSUB_OFF  24640u
#define CTRL_OFF   24840u
#define FINE_OFF   24864u
#define ZERO_WORDS 25376u
#define SAMP_OFF   25376u      // sample bits; consumed before kA writes gray
#define GRAY_OFF   25376u
#define GRAY_CAP   450000u
#define EB_OFF     (GRAY_OFF + GRAY_CAP)
#define CAND_OFF   25376u
#define CAND_CAP   880000u
#define LBUF       1024u
#define SLOTS      12u
#define DELTA_S    2500LL
#define VMARGIN    16384u
#define KA_GATE    4096.0f     // kA exact gate: err < 4096 << VMARGIN

#define FLOOR_BITS 0x36000000u

// CTRL: 0 b12(fb) | 1 kprime(fb) | 2 thr | 3 cand_cnt(fb) | 4 win_lo(fb)
// 5 kpp(fb) | 6 m_bin(fb) | 7 flag(0 main,1 fb,2 done) | 8 est_lo | 9 est_hi
// 10 gray_cnt | 11 above_cnt | 12 rank | 13 b12est | 14 bsel | 15 sft
// 16 rem | 17 lo_bin | 18 hi_bin | 19 ks | 20 nonzero_total | 21 slot_ovf

// --- exact softplus (UNCHANGED from passing rounds 1-12) -----------------
__device__ __forceinline__ float softplus_exact(float x) {
    float ax = fabsf(x);
    float e = (float)exp(-(double)ax);
    float l = (float)log1p((double)e);
    return fmaxf(x, 0.0f) + l;
}
__device__ __forceinline__ unsigned exact_bits(float x) {
    return __float_as_uint(softplus_exact(x));
}

// --- fallback/sampling refinement (r8-proven, UNCHANGED) -----------------
__device__ __forceinline__ unsigned refine_core(float x, float ax, float e,
                                                float sp) {
    unsigned cb = __float_as_uint(sp);
    float mf = 64.0f + 8.0f * ax;
    if (x < 0.0f) mf += __builtin_amdgcn_rcpf(e);
    bool need = (cb < FLOOR_BITS) || (mf >= 524288.0f);
    if (!need) {
        unsigned m = (unsigned)mf;
        unsigned low = cb & 0xFFFFFu;
        need = (low < m) || (low >= 0x100000u - m);
    }
    if (need) cb = exact_bits(x);
    return cb;
}
__device__ __forceinline__ unsigned refine_A(float x) {
    float ax = fabsf(x);
    float e = __expf(-ax);
    float sp = fmaxf(x, 0.0f) + __logf(1.0f + e);
    return refine_core(x, ax, e, sp);
}
__device__ __forceinline__ unsigned known_loss_bits(float x, float t) {
    float ax = fabsf(x);
    float e = __expf(-ax);
    float sp = fmaxf(x, 0.0f) + __logf(1.0f + e);
    return __float_as_uint(sp - x * t);
}

// ========================= sampling (k0a..k0d) ===========================
// k0a: sample-hist12 AND store sample bits to SAMP (8 per unit; 0 = known)
__global__ __launch_bounds__(256) void k0a_shist(
    const float* __restrict__ lg, const float* __restrict__ tg,
    unsigned* __restrict__ ws, long long n) {
    __shared__ unsigned sh[4096];
    for (int i = threadIdx.x; i < 4096; i += 256) sh[i] = 0;
    __syncthreads();
    long long units = n >> 9;
    long long u = (long long)blockIdx.x * 256 + threadIdx.x;
    if (u < units) {
        const f32x4* lg4 = (const f32x4*)lg;
        const f32x4* tg4 = (const f32x4*)tg;
        long long b = u * 128;
        f32x4 xa = lg4[b], xb = lg4[b + 1];
        f32x4 ta = tg4[b], tb = tg4[b + 1];
        float xs[8] = {xa.x, xa.y, xa.z, xa.w, xb.x, xb.y, xb.z, xb.w};
        float ts[8] = {ta.x, ta.y, ta.z, ta.w, tb.x, tb.y, tb.z, tb.w};
        unsigned cbs[8];
#pragma unroll
        for (int c = 0; c < 8; ++c) {
            unsigned cb = 0u;
            if (isnan(ts[c])) {
                cb = refine_A(xs[c]);
                if (cb) atomicAdd(&sh[cb >> 20], 1u);
            }
            cbs[c] = cb;
        }
        u32x4 s0 = {cbs[0], cbs[1], cbs[2], cbs[3]};
        u32x4 s1 = {cbs[4], cbs[5], cbs[6], cbs[7]};
        u32x4* samp4 = (u32x4*)(ws + SAMP_OFF);
        samp4[2 * u] = s0;
        samp4[2 * u + 1] = s1;
    }
    __syncthreads();
    for (int i = threadIdx.x; i < 4096; i += 256)
        if (sh[i]) atomicAdd(&ws[SH12_OFF + i], sh[i]);
}

__global__ __launch_bounds__(256) void k0b_sbin(
    unsigned* __restrict__ ws, const int* __restrict__ epoch_ptr) {
    const unsigned* sh12 = ws + SH12_OFF;
    unsigned* ctrl = ws + CTRL_OFF;
    __shared__ unsigned long long chunk[256];
    int t = threadIdx.x;
    unsigned long long s = 0;
    for (int j = 0; j < 16; ++j) s += sh12[t * 16 + j];
    chunk[t] = s;
    __syncthreads();
    if (t == 0) {
        unsigned long long tot = 0;
        for (int c = 0; c < 256; ++c) tot += chunk[c];
        if (tot == 0) {
            ctrl[7] = 1u;
            ctrl[8] = 0u; ctrl[9] = 0u; ctrl[19] = 0u;
            ctrl[17] = 0u; ctrl[18] = 0u;
            return;
        }
        int epoch = epoch_ptr[0];
        float percent = fminf((float)epoch * 0.1f, 1.0f);
        long long ks = (long long)((double)percent * (double)tot + 0.5);
        if (ks < 1) ks = 1;
        if (ks > (long long)tot) ks = (long long)tot;
        long long cum = 0;
        int bE = 0;
        for (int c = 255; c >= 0; --c) {
            if (cum + (long long)chunk[c] >= ks) {
                long long cc = cum;
                for (int j = 15; j >= 0; --j) {
                    unsigned v = sh12[c * 16 + j];
                    if (cc + (long long)v >= ks) { bE = c * 16 + j; break; }
                    cc += v;
                }
                break;
            }
            cum += chunk[c];
        }
        ctrl[13] = (unsigned)bE;
        ctrl[17] = (bE > 0) ? (unsigned)(bE - 1) : 0u;
        ctrl[18] = (bE < 4095) ? (unsigned)(bE + 1) : 4095u;
        ctrl[19] = (unsigned)ks;
    }
}

// k0c: sub-bin hist from STORED sample bits (no global rescan)
__global__ __launch_bounds__(256) void k0c_ssub(
    unsigned* __restrict__ ws, long long n) {
    if (ws[CTRL_OFF + 7] != 0u) return;
    unsigned lob = ws[CTRL_OFF + 17], hib = ws[CTRL_OFF + 18];
    unsigned rlo = lob << 20;
    unsigned rhi = (hib >= 4095u) ? 0xFFFFFFFFu : ((hib + 1u) << 20);
    __shared__ unsigned sh[192];
    if (threadIdx.x < 192) sh[threadIdx.x] = 0;
    __syncthreads();
    long long nsamp = (n >> 9) * 8;
    long long tid = (long long)blockIdx.x * 256 + threadIdx.x;
    long long stride = (long long)gridDim.x * 256;
    for (long long i = tid; i < nsamp; i += stride) {
        unsigned cb = ws[SAMP_OFF + i];
        if (cb != 0u && cb >= rlo && cb < rhi) {
            unsigned sub = (cb - rlo) >> 14;
            if (sub < 192u) atomicAdd(&sh[sub], 1u);
        }
    }
    __syncthreads();
    if (threadIdx.x < 192 && sh[threadIdx.x])
        atomicAdd(&ws[SHSUB_OFF + threadIdx.x], sh[threadIdx.x]);
}

__global__ __launch_bounds__(256) void k0d_window(unsigned* __restrict__ ws) {
    unsigned* ctrl = ws + CTRL_OFF;
    if (ctrl[7] != 0u) return;
    __shared__ unsigned long long red[256];
    __shared__ unsigned arr[192];
    int t = threadIdx.x;
    unsigned hib = ctrl[18];
    unsigned long long s = 0;
    for (int b = t; b < 4096; b += 256)
        if ((unsigned)b > hib) s += ws[SH12_OFF + b];
    red[t] = s;
    if (t < 192) arr[t] = ws[SHSUB_OFF + t];
    __syncthreads();
    for (int off = 128; off > 0; off >>= 1) {
        if (t < off) red[t] += red[t + off];
        __syncthreads();
    }
    if (t == 0) {
        unsigned lob = ctrl[17];
        unsigned base = lob << 20;
        int nsub = (int)(hib - lob + 1u) * 64;
        if (nsub > 192) nsub = 192;
        long long ks = (long long)ctrl[19];
        long long lo_t = ks - DELTA_S;
        long long hi_t = ks + DELTA_S;
        long long cum = (long long)red[0];
        unsigned est_hi = base + ((unsigned)nsub << 14);
        unsigned est_lo = base;
        bool fh = false, fl = false;
        for (int j = nsub - 1; j >= 0; --j) {
            if (!fh && cum + (long long)arr[j] > lo_t) {
                est_hi = base + ((unsigned)(j + 1) << 14);
                fh = true;
            }
            cum += arr[j];
            if (!fl && cum >= hi_t) {
                est_lo = base + ((unsigned)j << 14);
                fl = true;
            }
            if (fh && fl) break;
        }
        if (!fh) est_hi = base;
        ctrl[8] = est_lo;
        ctrl[9] = est_hi;
    }
}

// ========================= main pass kA (branchless classify) ============
// Lean exact gate: non-exact err < KA_GATE=4096 ulps << VMARGIN -> window
// classification provably safe. Only divergence: rare exact + gray store.
__device__ __forceinline__ unsigned kA_elem(float x, float t, unsigned idx,
                                            unsigned elo, unsigned ehi,
                                            unsigned& nz, unsigned& ab,
                                            unsigned& gc,
                                            unsigned* __restrict__ myslots) {
    float ax = fabsf(x);
    float e = __expf(-ax);
    float sp = fmaxf(x, 0.0f) + __logf(1.0f + e);
    bool unk = isnan(t);
    unsigned cb = __float_as_uint(sp);
    float mf = 64.0f + 8.0f * ax;
    mf = (x < 0.0f) ? mf + __builtin_amdgcn_rcpf(e) : mf;
    bool need = (cb < FLOOR_BITS) | (mf >= KA_GATE);
    if (need & unk) cb = exact_bits(x);              // ~1e-6 of elements
    unsigned kb = __float_as_uint(sp - x * t);
    bool above = unk & (cb >= ehi);
    bool gray  = unk & (cb >= elo) & (cb < ehi);
    nz += (unsigned)(unk & (cb != 0u));
    ab += (unsigned)above;
    if (gray) { if (gc < SLOTS) myslots[gc] = idx; ++gc; }   // ~1%
    return unk ? (above ? 0u : cb) : kb;
}

__global__ __launch_bounds__(256) void kA_main(
    const float* __restrict__ lg, const float* __restrict__ tg,
    float* __restrict__ out, unsigned* __restrict__ ws, long long n) {
    __shared__ unsigned slots[256 * SLOTS];          // 12 KB
    __shared__ unsigned buf[LBUF];                   // 4 KB
    __shared__ unsigned lcnt, gbase, snz, sab, ovf;
    if (threadIdx.x == 0) { lcnt = 0; snz = 0; sab = 0; ovf = 0; }
    __syncthreads();
    unsigned flag = ws[CTRL_OFF + 7];
    unsigned elo = ws[CTRL_OFF + 8], ehi = ws[CTRL_OFF + 9];
    if (flag != 0u) { elo = 0xFFFFFFFFu; ehi = 0xFFFFFFFFu; }
    unsigned nz = 0, ab = 0, gc = 0;
    unsigned* myslots = &slots[threadIdx.x * SLOTS];

    long long n8 = n >> 3;
    long long tid = (long long)blockIdx.x * 256 + threadIdx.x;
    long long stride = (long long)gridDim.x * 256;
    const f32x4* lg4 = (const f32x4*)lg;
    const f32x4* tg4 = (const f32x4*)tg;
    f32x4* out4 = (f32x4*)out;

    if (n8 % stride == 0) {
        // fast path: uniform iteration count, depth-2 prefetch
        long long iters = n8 / stride;
        f32x4 xa0, xb0, ta0, tb0, xa1, xb1, ta1, tb1;
        {
            long long i = tid;
            xa0 = lg4[2 * i]; xb0 = lg4[2 * i + 1];
            ta0 = __builtin_nontemporal_load(&tg4[2 * i]);
            tb0 = __builtin_nontemporal_load(&tg4[2 * i + 1]);
        }
        if (iters > 1) {
            long long i = tid + stride;
            xa1 = lg4[2 * i]; xb1 = lg4[2 * i + 1];
            ta1 = __builtin_nontemporal_load(&tg4[2 * i]);
            tb1 = __builtin_nontemporal_load(&tg4[2 * i + 1]);
        }
        for (long long it = 0; it < iters; ++it) {
            f32x4 pa, pb, pta, ptb;
            if (it + 2 < iters) {
                long long i = tid + (it + 2) * stride;
                pa = lg4[2 * i]; pb = lg4[2 * i + 1];
                pta = __builtin_nontemporal_load(&tg4[2 * i]);
                ptb = __builtin_nontemporal_load(&tg4[2 * i + 1]);
            }
            long long i = tid + it * stride;
            unsigned base = (unsigned)(i * 8);
            f32x4 oa, ob_;
            oa.x = __uint_as_float(kA_elem(xa0.x, ta0.x, base + 0, elo, ehi, nz, ab, gc, myslots));
            oa.y = __uint_as_float(kA_elem(xa0.y, ta0.y, base + 1, elo, ehi, nz, ab, gc, myslots));
            oa.z = __uint_as_float(kA_elem(xa0.z, ta0.z, base + 2, elo, ehi, nz, ab, gc, myslots));
            oa.w = __uint_as_float(kA_elem(xa0.w, ta0.w, base + 3, elo, ehi, nz, ab, gc, myslots));
            ob_.x = __uint_as_float(kA_elem(xb0.x, tb0.x, base + 4, elo, ehi, nz, ab, gc, myslots));
            ob_.y = __uint_as_float(kA_elem(xb0.y, tb0.y, base + 5, elo, ehi, nz, ab, gc, myslots));
            ob_.z = __uint_as_float(kA_elem(xb0.z, tb0.z, base + 6, elo, ehi, nz, ab, gc, myslots));
            ob_.w = __uint_as_float(kA_elem(xb0.w, tb0.w, base + 7, elo, ehi, nz, ab, gc, myslots));
            out4[2 * i] = oa;
            out4[2 * i + 1] = ob_;
            xa0 = xa1; xb0 = xb1; ta0 = ta1; tb0 = tb1;
            xa1 = pa; xb1 = pb; ta1 = pta; tb1 = ptb;
        }
    } else {
        for (long long i = tid; i < n8; i += stride) {
            f32x4 xa = lg4[2 * i], xb = lg4[2 * i + 1];
            f32x4 ta = tg4[2 * i], tb = tg4[2 * i + 1];
            unsigned base = (unsigned)(i * 8);
            f32x4 oa, ob_;
            oa.x = __uint_as_float(kA_elem(xa.x, ta.x, base + 0, elo, ehi, nz, ab, gc, myslots));
            oa.y = __uint_as_float(kA_elem(xa.y, ta.y, base + 1, elo, ehi, nz, ab, gc, myslots));
            oa.z = __uint_as_float(kA_elem(xa.z, ta.z, base + 2, elo, ehi, nz, ab, gc, myslots));
            oa.w = __uint_as_float(kA_elem(xa.w, ta.w, base + 3, elo, ehi, nz, ab, gc, myslots));
            ob_.x = __uint_as_float(kA_elem(xb.x, tb.x, base + 4, elo, ehi, nz, ab, gc, myslots));
            ob_.y = __uint_as_float(kA_elem(xb.y, tb.y, base + 5, elo, ehi, nz, ab, gc, myslots));
            ob_.z = __uint_as_float(kA_elem(xb.z, tb.z, base + 6, elo, ehi, nz, ab, gc, myslots));
            ob_.w = __uint_as_float(kA_elem(xb.w, tb.w, base + 7, elo, ehi, nz, ab, gc, myslots));
            out4[2 * i] = oa;
            out4[2 * i + 1] = ob_;
        }
    }
    if (tid == 0) {   // scalar tail (n % 8 == 0 here; kept for generality)
        for (long long q = (n >> 3) << 3; q < n; ++q)
            out[q] = __uint_as_float(
                kA_elem(lg[q], tg[q], (unsigned)q, elo, ehi, nz, ab, gc, myslots));
    }
    // ---- end-of-kernel drains (off the critical path) ----
    if (gc > SLOTS) atomicOr(&ovf, 1u);
    unsigned myc = (gc < SLOTS) ? gc : SLOTS;
    for (unsigned s2 = 0; s2 < myc; ++s2) {
        unsigned li = atomicAdd(&lcnt, 1u);
        if (li < LBUF) buf[li] = myslots[s2];
    }
    if (nz) atomicAdd(&snz, nz);
    if (ab) atomicAdd(&sab, ab);
    __syncthreads();
    if (threadIdx.x == 0) {
        if (snz) atomicAdd(&ws[CTRL_OFF + 20], snz);
        if (sab) atomicAdd(&ws[CTRL_OFF + 11], sab);
        if (ovf) ws[CTRL_OFF + 21] = 1u;
        unsigned add = (lcnt > LBUF) ? (GRAY_CAP + 1u) : lcnt;
        gbase = atomicAdd(&ws[CTRL_OFF + 10], add);
    }
    __syncthreads();
    unsigned c2 = lcnt < LBUF ? lcnt : LBUF;
    for (unsigned q = threadIdx.x; q < c2; q += 256) {
        unsigned gi = gbase + q;
        if (gi < GRAY_CAP) ws[GRAY_OFF + gi] = buf[q];
    }
}

// ========================= k2: exact k + routing =========================
__global__ void k2_route(unsigned* __restrict__ ws,
                         const int* __restrict__ epoch_ptr) {
    if (threadIdx.x != 0) return;
    unsigned* ctrl = ws + CTRL_OFF;
    unsigned tot = ctrl[20];
    int epoch = epoch_ptr[0];
    float percent = fminf((float)epoch * 0.1f, 1.0f);
    float nf = (float)tot;                 // astype(float32)
    float kr = rintf(nf * percent);        // jnp.round half-to-even
    long long k = (long long)kr;
    if (k < 1) k = 1;
    if (tot == 0u) { ctrl[2] = 0u; ctrl[7] = 2u; return; }  // trivial
    if (ctrl[7] != 0u) return;             // sampling already failed
    if (ctrl[21] != 0u) { ctrl[7] = 1u; return; }           // slot overflow
    unsigned g = ctrl[10], a = ctrl[11];
    unsigned elo = ctrl[8], ehi = ctrl[9];
    long long rank = k - (long long)a;
    if (g > GRAY_CAP || rank < 1 || rank > (long long)g ||
        ehi < elo + 2u * VMARGIN) {
        ctrl[7] = 1u;
        return;
    }
    ctrl[12] = (unsigned)rank;
    unsigned W = ehi - elo;
    unsigned sft = 0;
    while (((unsigned long long)16384u << sft) < (unsigned long long)W) ++sft;
    ctrl[15] = sft;
}

// ========================= gray selection ================================
__global__ __launch_bounds__(256) void G1_exact(
    const float* __restrict__ lg, unsigned* __restrict__ ws) {
    if (ws[CTRL_OFF + 7] != 0u) return;
    unsigned gcount = ws[CTRL_OFF + 10];
    unsigned elo = ws[CTRL_OFF + 8], ehi = ws[CTRL_OFF + 9];
    unsigned sft = ws[CTRL_OFF + 15];
    long long tid = (long long)blockIdx.x * 256 + threadIdx.x;
    long long stride = (long long)gridDim.x * 256;
    for (long long g = tid; g < (long long)gcount; g += stride) {
        unsigned idx = ws[GRAY_OFF + g];
        unsigned eb = exact_bits(lg[idx]);
        ws[EB_OFF + g] = eb;
        unsigned bin = (eb < elo) ? 0u
                     : (eb >= ehi) ? 16383u : ((eb - elo) >> sft);
        if (bin > 16383u) bin = 16383u;
        atomicAdd(&ws[HBIG_OFF + bin], 1u);
    }
}

__global__ __launch_bounds__(1024) void G2a_selbin(unsigned* __restrict__ ws) {
    unsigned* ctrl = ws + CTRL_OFF;
    if (ctrl[7] != 0u) return;
    __shared__ unsigned long long csum[1024];
    int t = threadIdx.x;
    unsigned long long s = 0;
    for (int j = 0; j < 16; ++j) s += ws[HBIG_OFF + t * 16 + j];
    csum[t] = s;
    __syncthreads();
    if (t == 0) {
        long long rank = (long long)ctrl[12];
        long long cum = 0;
        int sel = -1;
        long long rem = 1;
        for (int c = 1023; c >= 0; --c) {
            if (cum + (long long)csum[c] >= rank) {
                long long cc = cum;
                for (int j = 15; j >= 0; --j) {
                    unsigned v = ws[HBIG_OFF + c * 16 + j];
                    if (cc + (long long)v >= rank) {
                        sel = c * 16 + j; rem = rank - cc; break;
                    }
                    cc += v;
                }
                break;
            }
            cum += csum[c];
        }
        if (sel < 0) { ctrl[7] = 1u; return; }
        ctrl[14] = (unsigned)sel;
        ctrl[16] = (unsigned)rem;
    }
}

__global__ __launch_bounds__(256) void G2b_fine(unsigned* __restrict__ ws) {
    if (ws[CTRL_OFF + 7] != 0u) return;
    unsigned gcount = ws[CTRL_OFF + 10];
    unsigned elo = ws[CTRL_OFF + 8], ehi = ws[CTRL_OFF + 9];
    unsigned sft = ws[CTRL_OFF + 15];
    unsigned bsel = ws[CTRL_OFF + 14];
    long long tid = (long long)blockIdx.x * 256 + threadIdx.x;
    long long stride = (long long)gridDim.x * 256;
    for (long long g = tid; g < (long long)gcount; g += stride) {
        unsigned eb = ws[EB_OFF + g];
        if (eb >= elo && eb < ehi) {
            unsigned off = eb - elo;
            if ((off >> sft) == bsel)
                atomicAdd(&ws[FINE_OFF + (off - (bsel << sft))], 1u);
        }
    }
}

__global__ __launch_bounds__(512) void G2c_thr(unsigned* __restrict__ ws) {
    unsigned* ctrl = ws + CTRL_OFF;
    if (ctrl[7] != 0u) return;
    __shared__ unsigned fine[512];
    int t = threadIdx.x;
    unsigned sft = ctrl[15];
    unsigned binw = 1u << sft;
    if (binw > 512u) { if (t == 0) ctrl[7] = 1u; return; }
    if ((unsigned)t < binw) fine[t] = ws[FINE_OFF + t];
    __syncthreads();
    if (t == 0) {
        unsigned elo = ctrl[8], ehi = ctrl[9];
        unsigned binlo = elo + (ctrl[14] << sft);
        long long rem = (long long)ctrl[16];
        long long cum = 0;
        bool found = false;
        unsigned thr = 0;
        for (int o = (int)binw - 1; o >= 0; --o) {
            cum += fine[o];
            if (cum >= rem) { thr = binlo + (unsigned)o; found = true; break; }
        }
        if (!found || thr < elo + VMARGIN || thr > ehi - VMARGIN)
            ctrl[7] = 1u;
        else
            ctrl[2] = thr;
    }
}

__global__ __launch_bounds__(256) void kD_fix(
    unsigned* __restrict__ ob, const unsigned* __restrict__ ws) {
    if (ws[CTRL_OFF + 7] != 0u) return;
    unsigned gcount = ws[CTRL_OFF + 10];
    unsigned thr = ws[CTRL_OFF + 2];
    long long tid = (long long)blockIdx.x * 256 + threadIdx.x;
    long long stride = (long long)gridDim.x * 256;
    for (long long g = tid; g < (long long)gcount; g += stride) {
        if (ws[EB_OFF + g] > thr) ob[ws[GRAY_OFF + g]] = 0u;
    }
}

// ========================= fallback chain (r8-proven) ====================
__global__ __launch_bounds__(256) void fkA_hist(
    const float* __restrict__ lg, const float* __restrict__ tg,
    unsigned* __restrict__ ws, long long n) {
    if (ws[CTRL_OFF + 7] != 1u) return;
    __shared__ unsigned sh[4096];
    for (int i = threadIdx.x; i < 4096; i += 256) sh[i] = 0;
    __syncthreads();
    long long n4 = n >> 2;
    long long tid = (long long)blockIdx.x * 256 + threadIdx.x;
    long long stride = (long long)gridDim.x * 256;
    const f32x4* lg4 = (const f32x4*)lg;
    const f32x4* tg4 = (const f32x4*)tg;
    for (long long i = tid; i < n4; i += stride) {
        f32x4 x4 = lg4[i], t4 = tg4[i];
        float xs[4] = {x4.x, x4.y, x4.z, x4.w};
        float ts[4] = {t4.x, t4.y, t4.z, t4.w};
#pragma unroll
        for (int c = 0; c < 4; ++c)
            if (isnan(ts[c])) {
                unsigned cb = refine_A(xs[c]);
                if (cb) atomicAdd(&sh[cb >> 20], 1u);
            }
    }
    if (tid == 0) {
        for (long long q = (n4 << 2); q < n; ++q)
            if (isnan(tg[q])) {
                unsigned cb = refine_A(lg[q]);
                if (cb) atomicAdd(&sh[cb >> 20], 1u);
            }
    }
    __syncthreads();
    for (int i = threadIdx.x; i < 4096; i += 256)
        if (sh[i]) atomicAdd(&ws[H12_OFF + i], sh[i]);
}

__global__ __launch_bounds__(256) void fk2_sel(
    unsigned* __restrict__ ws, const int* __restrict__ epoch_ptr) {
    unsigned* ctrl = ws + CTRL_OFF;
    if (ctrl[7] != 1u) return;
    for (unsigned i = threadIdx.x; i < 16384u; i += 256) ws[HBIG_OFF + i] = 0;
    const unsigned* hist12 = ws + H12_OFF;
    __shared__ unsigned long long chunk[256];
    int t = threadIdx.x;
    unsigned long long s = 0;
    for (int j = 0; j < 16; ++j) s += hist12[t * 16 + j];
    chunk[t] = s;
    __syncthreads();
    if (t == 0) {
        unsigned long long tot = 0;
        for (int c = 0; c < 256; ++c) tot += chunk[c];
        if (tot == 0) { ctrl[2] = 0u; ctrl[7] = 2u; return; }
        int epoch = epoch_ptr[0];
        float percent = fminf((float)epoch * 0.1f, 1.0f);
        float nf = (float)tot;
        float kr = rintf(nf * percent);
        long long k = (long long)kr;
        if (k < 1) k = 1;
        long long cum = 0;
        int b = -1;
        long long kprime = 0;
        for (int c = 255; c >= 0; --c) {
            if (cum + (long long)chunk[c] >= k) {
                long long cc = cum;
                for (int j = 15; j >= 0; --j) {
                    unsigned v = hist12[c * 16 + j];
                    if (cc + (long long)v >= k) {
                        b = c * 16 + j; kprime = k - cc; break;
                    }
                    cc += v;
                }
                break;
            }
            cum += chunk[c];
        }
        ctrl[0] = (unsigned)b;
        ctrl[1] = (unsigned)kprime;
        unsigned lo12 = (unsigned)b << 20;
        double vlo = (double)__uint_as_float(lo12);
        double vhi = (double)__uint_as_float(lo12 + 0xFFFFFu);
        double mb = 1e9;
        if (vlo > 1e-30) {
            double xlo = vlo + log1p(-exp(-vlo)) - 0.001;
            double xhi = vhi + log1p(-exp(-vhi)) + 0.001;
            double axmax = fmax(fabs(xlo), fabs(xhi));
            mb = 64.0 + 8.0 * ceil(axmax);
            if (xlo < 0.0) mb += exp(fmin(-xlo, 30.0));
            mb *= 2.0;
        }
        ctrl[6] = (mb >= 8192.0) ? 8192u : (unsigned)mb;
    }
}

__global__ __launch_bounds__(256) void fkB(
    const float* __restrict__ lg, const float* __restrict__ tg,
    unsigned* __restrict__ ws, long long n) {
    if (ws[CTRL_OFF + 7] != 1u) return;
    unsigned b12 = ws[CTRL_OFF + 0];
    unsigned lo12 = b12 << 20, hi12 = lo12 + (1u << 20);
    unsigned m = ws[CTRL_OFF + 6];
    __shared__ unsigned sh[64];
    __shared__ float buf[LBUF];
    __shared__ unsigned lcnt, gbase;
    if (threadIdx.x < 64) sh[threadIdx.x] = 0;
    if (threadIdx.x == 0) lcnt = 0;
    __syncthreads();
    float* cand = (float*)(ws + CAND_OFF);
    unsigned* cnt = ws + CTRL_OFF + 3;
    long long n4 = n >> 2;
    long long tid = (long long)blockIdx.x * 256 + threadIdx.x;
    long long stride = (long long)gridDim.x * 256;
    const f32x4* lg4 = (const f32x4*)lg;
    const f32x4* tg4 = (const f32x4*)tg;
    for (long long i = tid; i < n4; i += stride) {
        f32x4 x4 = lg4[i], t4 = tg4[i];
        float xs[4] = {x4.x, x4.y, x4.z, x4.w};
        float ts[4] = {t4.x, t4.y, t4.z, t4.w};
#pragma unroll
        for (int c = 0; c < 4; ++c) {
            if (isnan(ts[c])) {
                float x = xs[c];
                unsigned cb = refine_A(x);
                if (cb >= lo12 && cb < hi12) {
                    unsigned d = cb & 16383u;
                    unsigned rB = (d < m || d >= 16384u - m) ? exact_bits(x) : cb;
                    atomicAdd(&sh[(rB >> 14) & 63u], 1u);
                    unsigned li = atomicAdd(&lcnt, 1u);
                    if (li < LBUF) buf[li] = x;
                }
            }
        }
    }
    if (tid == 0) {
        for (long long q = (n4 << 2); q < n; ++q) {
            if (isnan(tg[q])) {
                float x = lg[q];
                unsigned cb = refine_A(x);
                if (cb >= lo12 && cb < hi12) {
                    unsigned d = cb & 16383u;
                    unsigned rB = (d < m || d >= 16384u - m) ? exact_bits(x) : cb;
                    atomicAdd(&sh[(rB >> 14) & 63u], 1u);
                    unsigned idx = atomicAdd(cnt, 1u);
                    if (idx < CAND_CAP) cand[idx] = x;
                }
            }
        }
    }
    __syncthreads();
    if (threadIdx.x < 64 && sh[threadIdx.x])
        atomicAdd(&ws[H64_OFF + threadIdx.x], sh[threadIdx.x]);
    if (threadIdx.x == 0) {
        unsigned add = (lcnt > LBUF) ? (CAND_CAP + 1u) : lcnt;
        gbase = atomicAdd(cnt, add);
    }
    __syncthreads();
    unsigned c2 = lcnt < LBUF ? lcnt : LBUF;
    for (unsigned q = threadIdx.x; q < c2; q += 256) {
        unsigned gi = gbase + q;
        if (gi < CAND_CAP) cand[gi] = buf[q];
    }
}

__global__ void fk4(unsigned* __restrict__ ws) {
    unsigned* ctrl = ws + CTRL_OFF;
    if (ctrl[7] != 1u) return;
    if (threadIdx.x == 0) {
        long long kprime = (long long)ctrl[1];
        long long cum = 0;
        int s = 0;
        long long kpp = 1;
        for (int j = 63; j >= 0; --j) {
            unsigned v = ws[H64_OFF + j];
            if (cum + (long long)v >= kprime) { s = j; kpp = kprime - cum; break; }
            cum += v;
        }
        ctrl[4] = (ctrl[0] << 20) + ((unsigned)s << 14);
        ctrl[5] = (unsigned)kpp;
    }
}

__global__ __launch_bounds__(256) void fkC(
    const float* __restrict__ lg, const float* __restrict__ tg,
    unsigned* __restrict__ ws, long long n) {
    if (ws[CTRL_OFF + 7] != 1u) return;
    unsigned wlo = ws[CTRL_OFF + 4];
    unsigned whi = wlo + 16384u;
    unsigned m = ws[CTRL_OFF + 6];
    unsigned b12 = ws[CTRL_OFF + 0];
    unsigned lo12 = b12 << 20, hi12 = lo12 + (1u << 20);
    unsigned glo = (wlo - lo12 > m) ? wlo - m : lo12;
    unsigned ghi = (hi12 - whi > m) ? whi + m : hi12;
    unsigned count = ws[CTRL_OFF + 3];
    long long tid = (long long)blockIdx.x * 256 + threadIdx.x;
    long long stride = (long long)gridDim.x * 256;
    if (count <= CAND_CAP) {
        const float* cand = (const float*)(ws + CAND_OFF);
        for (long long i = tid; i < (long long)count; i += stride) {
            float x = cand[i];
            unsigned u = refine_A(x);
            if (u >= glo && u < ghi) {
                unsigned eb = exact_bits(x);
                unsigned d = u & 16383u;
                unsigned rB = (d < m || d >= 16384u - m) ? eb : u;
                if (rB >= wlo && rB < whi) {
                    unsigned off = eb - wlo;
                    if (off < 16384u) atomicAdd(&ws[HBIG_OFF + off], 1u);
                }
            }
        }
    } else {
        for (long long q = tid; q < n; q += stride) {
            if (isnan(tg[q])) {
                float x = lg[q];
                unsigned u = refine_A(x);
                if (u >= glo && u < ghi) {
                    unsigned eb = exact_bits(x);
                    unsigned d = u & 16383u;
                    unsigned rB = (d < m || d >= 16384u - m) ? eb : u;
                    if (rB >= wlo && rB < whi) {
                        unsigned off = eb - wlo;
                        if (off < 16384u) atomicAdd(&ws[HBIG_OFF + off], 1u);
                    }
                }
            }
        }
    }
}

__global__ __launch_bounds__(1024) void fk6(unsigned* __restrict__ ws) {
    unsigned* ctrl = ws + CTRL_OFF;
    if (ctrl[7] != 1u) return;
    __shared__ unsigned long long csum[1024];
    int t = threadIdx.x;
    unsigned long long s = 0;
    for (int j = 0; j < 16; ++j) s += ws[HBIG_OFF + t * 16 + j];
    csum[t] = s;
    __syncthreads();
    if (t == 0) {
        long long kpp = (long long)ctrl[5];
        long long cum = 0;
        int sel = 0;
        long long rem = kpp;
        for (int c = 1023; c >= 0; --c) {
            if (cum + (long long)csum[c] >= kpp) { sel = c; rem = kpp - cum; break; }
            cum += csum[c];
        }
        long long cc = 0;
        int bsel = 0;
        for (int j = 15; j >= 0; --j) {
            unsigned v = ws[HBIG_OFF + sel * 16 + j];
            if (cc + (long long)v >= rem) { bsel = j; break; }
            cc += v;
        }
        ctrl[2] = ctrl[4] + (unsigned)(sel * 16 + bsel);
    }
}

__global__ __launch_bounds__(256) void fkD(
    const float* __restrict__ lg, const float* __restrict__ tg,
    float* __restrict__ out, const unsigned* __restrict__ ws, long long n) {
    if (ws[CTRL_OFF + 7] != 1u) return;
    unsigned thr = ws[CTRL_OFF + 2];
    unsigned m = ws[CTRL_OFF + 6];
    long long n4 = n >> 2;
    long long tid = (long long)blockIdx.x * 256 + threadIdx.x;
    long long stride = (long long)gridDim.x * 256;
    const f32x4* lg4 = (const f32x4*)lg;
    const f32x4* tg4 = (const f32x4*)tg;
    f32x4* out4 = (f32x4*)out;
    for (long long i = tid; i < n4; i += stride) {
        f32x4 x4 = lg4[i], t4 = tg4[i];
        float xs[4] = {x4.x, x4.y, x4.z, x4.w};
        float ts[4] = {t4.x, t4.y, t4.z, t4.w};
        f32x4 o;
        float os[4];
#pragma unroll
        for (int c = 0; c < 4; ++c) {
            float x = xs[c], t = ts[c];
            if (isnan(t)) {
                unsigned cb = refine_A(x);
                unsigned udiff = (cb > thr) ? cb - thr : thr - cb;
                unsigned r;
                if (udiff <= m) {
                    unsigned eb = exact_bits(x);
                    r = (eb > thr) ? 0u : eb;
                } else {
                    r = (cb > thr) ? 0u : cb;
                }
                os[c] = __uint_as_float(r);
            } else {
                os[c] = __uint_as_float(known_loss_bits(x, t));
            }
        }
        o.x = os[0]; o.y = os[1]; o.z = os[2]; o.w = os[3];
        out4[i] = o;
    }
    if (tid == 0) {
        for (long long q = (n4 << 2); q < n; ++q) {
            float x = lg[q], t = tg[q];
            if (isnan(t)) {
                unsigned cb = refine_A(x);
                unsigned udiff = (cb > thr) ? cb - thr : thr - cb;
                unsigned eb, r;
                if (udiff <= m) { eb = exact_bits(x); r = (eb > thr) ? 0u : eb; }
                else r = (cb > thr) ? 0u : cb;
                out[q] = __uint_as_float(r);
            } else {
                out[q] = __uint_as_float(known_loss_bits(x, t));
            }
        }
    }
}

extern "C" void kernel_launch(void* const* d_in, const int* in_sizes, int n_in,
                              void* d_out, int out_size, void* d_ws, size_t ws_size,
                              hipStream_t stream) {
    const float* lg = (const float*)d_in[0];
    const float* tg = (const float*)d_in[1];
    const int* epoch = (const int*)d_in[2];
    float* out = (float*)d_out;
    unsigned* ob = (unsigned*)d_out;
    unsigned* ws = (unsigned*)d_ws;
    long long n = (long long)in_sizes[0];

    (void)hipMemsetAsync(d_ws, 0, (size_t)ZERO_WORDS * 4, stream);

    k0a_shist<<<256, 256, 0, stream>>>(lg, tg, ws, n);
    k0b_sbin<<<1, 256, 0, stream>>>(ws, epoch);
    k0c_ssub<<<256, 256, 0, stream>>>(ws, n);
    k0d_window<<<1, 256, 0, stream>>>(ws);
    kA_main<<<2048, 256, 0, stream>>>(lg, tg, out, ws, n);
    k2_route<<<1, 64, 0, stream>>>(ws, epoch);
    G1_exact<<<128, 256, 0, stream>>>(lg, ws);
    G2a_selbin<<<1, 1024, 0, stream>>>(ws);
    G2b_fine<<<128, 256, 0, stream>>>(ws);
    G2c_thr<<<1, 512, 0, stream>>>(ws);
    kD_fix<<<128, 256, 0, stream>>>(ob, ws);
    // fallback chain (early-exits unless ctrl[7]==1)
    fkA_hist<<<1024, 256, 0, stream>>>(lg, tg, ws, n);
    fk2_sel<<<1, 256, 0, stream>>>(ws, epoch);
    fkB<<<1024, 256, 0, stream>>>(lg, tg, ws, n);
    fk4<<<1, 64, 0, stream>>>(ws);
    fkC<<<512, 256, 0, stream>>>(lg, tg, ws, n);
    fk6<<<1, 1024, 0, stream>>>(ws);
    fkD<<<2048, 256, 0, stream>>>(lg, tg, out, ws, n);
}

// Round 14
// 244.986 us; speedup vs baseline: 1.1600x; 1.1600x over previous
//
#include <hip/hip_runtime.h>
#include <math.h>

typedef float    f32x4 __attribute__((ext_vector_type(4)));
typedef unsigned u32x4 __attribute__((ext_vector_type(4)));

// ws layout (uint32 words)  — r8-proven architecture:
//   [0     .. 16384)  histC  (exact low-bits hist over selected 2^14 window)
//   [16384 .. 20480)  hist12 (top-12-bit histogram)
//   [20480 .. 20544)  hist64 (64 sub-bins of width 2^14 within selected b12)
//   [20544 .. 20560)  ctrl: [0]=b12 [1]=kprime [2]=thr_bits [3]=cand_count
//                           [4]=win_lo [5]=kpp [6]=m_bin
//   [20560 .. +CAP)   candidate x values (float) of selected b12
#define HC_OFF     0u
#define H12_OFF    16384u
#define H64_OFF    20480u
#define CTRL_OFF   20544u
#define ZERO_WORDS 20560u
#define CAND_OFF   20560u
#define CAND_CAP   900000u
#define LBUF       2048u

#define FLOOR_BITS 0x36000000u // bits(2^-19): below this, cheap unreliable

// TAGGING (r9-proven): known -> loss_bits & ~1 (even, FINAL);
// unknown -> refined_bits | 1 (odd). <=1-ulp perturbation absorbed by
// margins (+2); bin membership at 2^20/2^14 tag-invariant; exact threshold
// bits stay untagged.

// --- exact softplus (UNCHANGED from passing rounds 1-13) -----------------
__device__ __forceinline__ float softplus_exact(float x) {
    float ax = fabsf(x);
    float e = (float)exp(-(double)ax);
    float l = (float)log1p((double)e);
    return fmaxf(x, 0.0f) + l;
}
__device__ __forceinline__ unsigned exact_bits(float x) {
    return __float_as_uint(softplus_exact(x));
}

// --- refinement: cheap + margin-gated exact; DETERMINISTIC fn of x -------
__device__ __forceinline__ unsigned refine_core(float x, float ax, float e,
                                                float sp) {
    unsigned cb = __float_as_uint(sp);
    float mf = 64.0f + 8.0f * ax;
    if (x < 0.0f) mf += __builtin_amdgcn_rcpf(e);
    bool need = (cb < FLOOR_BITS) || (mf >= 524288.0f);
    if (!need) {
        unsigned m = (unsigned)mf;
        unsigned low = cb & 0xFFFFFu;
        need = (low < m) || (low >= 0x100000u - m);
    }
    if (need) cb = exact_bits(x);
    return cb;
}
__device__ __forceinline__ unsigned refine_A(float x) {
    float ax = fabsf(x);
    float e = __expf(-ax);
    float sp = fmaxf(x, 0.0f) + __logf(1.0f + e);
    return refine_core(x, ax, e, sp);
}

// --- kA per-element: branchless shared exp/log core (r9-proven) ----------
__device__ __forceinline__ unsigned kA_elem(float x, float t,
                                            unsigned* __restrict__ sh) {
    float ax = fabsf(x);
    float e = __expf(-ax);
    float sp = fmaxf(x, 0.0f) + __logf(1.0f + e);
    unsigned outb;
    if (isnan(t)) {
        unsigned cb = refine_core(x, ax, e, sp) | 1u;   // tag odd
        if (cb != 1u) atomicAdd(&sh[cb >> 20], 1u);     // count_nonzero
        outb = cb;
    } else {
        float loss = sp - x * t;                    // >= 0 always
        outb = __float_as_uint(loss) & ~1u;         // tag even: FINAL value
    }
    return outb;
}

// --- kA: stream logits+targets; store tagged bits to out; hist12 ---------
__global__ __launch_bounds__(256) void kA_store_hist(
    const float* __restrict__ lg, const float* __restrict__ tg,
    float* __restrict__ out, unsigned* __restrict__ ws, long long n) {
    __shared__ unsigned sh[4096];
    for (int i = threadIdx.x; i < 4096; i += 256) sh[i] = 0;
    __syncthreads();

    long long n8 = n >> 3;
    long long tid = (long long)blockIdx.x * 256 + threadIdx.x;
    long long stride = (long long)gridDim.x * 256;
    const f32x4* lg4 = (const f32x4*)lg;
    const f32x4* tg4 = (const f32x4*)tg;
    f32x4* out4 = (f32x4*)out;

    if (n8 % stride == 0) {
        // fast path: uniform iteration count, depth-2 prefetch (r9: 108 us)
        long long iters = n8 / stride;
        f32x4 xa0, xb0, ta0, tb0, xa1, xb1, ta1, tb1;
        {
            long long i = tid;
            xa0 = lg4[2 * i]; xb0 = lg4[2 * i + 1];
            ta0 = __builtin_nontemporal_load(&tg4[2 * i]);
            tb0 = __builtin_nontemporal_load(&tg4[2 * i + 1]);
        }
        if (iters > 1) {
            long long i = tid + stride;
            xa1 = lg4[2 * i]; xb1 = lg4[2 * i + 1];
            ta1 = __builtin_nontemporal_load(&tg4[2 * i]);
            tb1 = __builtin_nontemporal_load(&tg4[2 * i + 1]);
        }
        for (long long it = 0; it < iters; ++it) {
            f32x4 pa, pb, pta, ptb;
            if (it + 2 < iters) {
                long long i = tid + (it + 2) * stride;
                pa = lg4[2 * i]; pb = lg4[2 * i + 1];
                pta = __builtin_nontemporal_load(&tg4[2 * i]);
                ptb = __builtin_nontemporal_load(&tg4[2 * i + 1]);
            }
            long long i = tid + it * stride;
            f32x4 oa, ob_;
            oa.x = __uint_as_float(kA_elem(xa0.x, ta0.x, sh));
            oa.y = __uint_as_float(kA_elem(xa0.y, ta0.y, sh));
            oa.z = __uint_as_float(kA_elem(xa0.z, ta0.z, sh));
            oa.w = __uint_as_float(kA_elem(xa0.w, ta0.w, sh));
            ob_.x = __uint_as_float(kA_elem(xb0.x, tb0.x, sh));
            ob_.y = __uint_as_float(kA_elem(xb0.y, tb0.y, sh));
            ob_.z = __uint_as_float(kA_elem(xb0.z, tb0.z, sh));
            ob_.w = __uint_as_float(kA_elem(xb0.w, tb0.w, sh));
            out4[2 * i] = oa;
            out4[2 * i + 1] = ob_;
            xa0 = xa1; xb0 = xb1; ta0 = ta1; tb0 = tb1;
            xa1 = pa; xb1 = pb; ta1 = pta; tb1 = ptb;
        }
    } else {
        for (long long i = tid; i < n8; i += stride) {
            f32x4 xa = lg4[2 * i], xb = lg4[2 * i + 1];
            f32x4 ta = tg4[2 * i], tb = tg4[2 * i + 1];
            f32x4 oa, ob_;
            oa.x = __uint_as_float(kA_elem(xa.x, ta.x, sh));
            oa.y = __uint_as_float(kA_elem(xa.y, ta.y, sh));
            oa.z = __uint_as_float(kA_elem(xa.z, ta.z, sh));
            oa.w = __uint_as_float(kA_elem(xa.w, ta.w, sh));
            ob_.x = __uint_as_float(kA_elem(xb.x, tb.x, sh));
            ob_.y = __uint_as_float(kA_elem(xb.y, tb.y, sh));
            ob_.z = __uint_as_float(kA_elem(xb.z, tb.z, sh));
            ob_.w = __uint_as_float(kA_elem(xb.w, tb.w, sh));
            out4[2 * i] = oa;
            out4[2 * i + 1] = ob_;
        }
    }
    if (tid == 0) {   // scalar tail
        for (long long q = (n >> 3) << 3; q < n; ++q)
            out[q] = __uint_as_float(kA_elem(lg[q], tg[q], sh));
    }
    __syncthreads();
    unsigned* hist12 = ws + H12_OFF;
    for (int q = threadIdx.x; q < 4096; q += 256)
        if (sh[q]) atomicAdd(&hist12[q], sh[q]);
}

// --- k2: select 12-bit bin; compute k, kprime, and bin-wide margin -------
__global__ __launch_bounds__(256) void k2_sel12(
    unsigned* __restrict__ ws, const int* __restrict__ epoch_ptr) {
    const unsigned* hist12 = ws + H12_OFF;
    unsigned* ctrl = ws + CTRL_OFF;
    __shared__ unsigned long long chunk[256];
    int t = threadIdx.x;
    unsigned long long s = 0;
    for (int j = 0; j < 16; ++j) s += hist12[t * 16 + j];
    chunk[t] = s;
    __syncthreads();
    if (t == 0) {
        unsigned long long tot = 0;
        for (int c = 0; c < 256; ++c) tot += chunk[c];
        int epoch = epoch_ptr[0];
        float percent = fminf((float)epoch * 0.1f, 1.0f);
        float nf = (float)tot;              // astype(float32)
        float kr = rintf(nf * percent);     // jnp.round half-to-even
        long long k = (long long)kr;        // astype(int32)
        if (k < 1) k = 1;

        long long cum = 0;
        int b = -1;
        long long kprime = 0;
        for (int c = 255; c >= 0; --c) {
            if (cum + (long long)chunk[c] >= k) {
                long long cc = cum;
                for (int j = 15; j >= 0; --j) {
                    unsigned v = hist12[c * 16 + j];
                    if (cc + (long long)v >= k) {
                        b = c * 16 + j;
                        kprime = k - cc;
                        break;
                    }
                    cc += v;
                }
                break;
            }
            cum += chunk[c];
        }
        ctrl[0] = (unsigned)b;
        ctrl[1] = (unsigned)kprime;
        if (b < 0) {
            ctrl[2] = 0u;                   // threshold = 0.0f
            ctrl[4] = 0xFFFFFFFFu;          // no window
            ctrl[6] = 0u;
        } else {
            unsigned lo12 = (unsigned)b << 20;
            double vlo = (double)__uint_as_float(lo12);
            double vhi = (double)__uint_as_float(lo12 + 0xFFFFFu);
            double mb = 1e9;
            if (vlo > 1e-30) {
                double xlo = vlo + log1p(-exp(-vlo)) - 0.001;  // inv_softplus
                double xhi = vhi + log1p(-exp(-vhi)) + 0.001;
                double axmax = fmax(fabs(xlo), fabs(xhi));
                mb = 64.0 + 8.0 * ceil(axmax);
                if (xlo < 0.0) mb += exp(fmin(-xlo, 30.0));
                mb *= 2.0;                  // safety factor
            }
            ctrl[6] = (mb >= 8192.0) ? 8192u : (unsigned)mb;
        }
    }
}

// --- kB: 64-sub-bin histogram within selected bin + candidate compaction --
__global__ __launch_bounds__(256) void kB_hist64(
    const float* __restrict__ lg, const unsigned* __restrict__ ob,
    unsigned* __restrict__ ws, long long n) {
    unsigned b12 = ws[CTRL_OFF + 0];
    if (b12 == 0xFFFFFFFFu) return;
    unsigned lo12 = b12 << 20;
    unsigned hi12 = lo12 + (1u << 20);
    unsigned medge = ws[CTRL_OFF + 6] + 2u;   // +2: tag absorption

    __shared__ unsigned sh[64];
    __shared__ float buf[LBUF];
    __shared__ unsigned lcnt, gbase;
    if (threadIdx.x < 64) sh[threadIdx.x] = 0;
    if (threadIdx.x == 0) lcnt = 0;
    __syncthreads();

    float* cand = (float*)(ws + CAND_OFF);
    unsigned* cnt = ws + CTRL_OFF + 3;

    long long n4 = n >> 2;
    long long tid = (long long)blockIdx.x * 256 + threadIdx.x;
    long long stride = (long long)gridDim.x * 256;
    const u32x4* o4 = (const u32x4*)ob;

    long long i = tid;
    u32x4 u4;
    if (i < n4) u4 = o4[i];
    while (i < n4) {
        long long j = i + stride;
        u32x4 nu4;
        if (j < n4) nu4 = o4[j];            // prefetch next tile
        unsigned us[4] = {u4.x, u4.y, u4.z, u4.w};
#pragma unroll
        for (int c = 0; c < 4; ++c) {
            unsigned u = us[c];
            // unknown = odd; u==1 is true-zero loss (excluded by count_nonzero)
            if ((u & 1u) && u != 1u && u >= lo12 && u < hi12) {
                float x = lg[i * 4 + c];
                unsigned rB = u;
                unsigned d = u & 16383u;
                if (d < medge || d >= 16384u - medge)
                    rB = exact_bits(x) | 1u;      // edge: exact (tagged bin)
                atomicAdd(&sh[(rB >> 14) & 63u], 1u);
                unsigned li = atomicAdd(&lcnt, 1u);   // LDS atomic
                if (li < LBUF) buf[li] = x;
            }
        }
        u4 = nu4;
        i = j;
    }
    if (tid == 0) {  // scalar tail (empty for n % 4 == 0): direct append
        for (long long q = (n4 << 2); q < n; ++q) {
            unsigned u = ob[q];
            if ((u & 1u) && u != 1u && u >= lo12 && u < hi12) {
                float x = lg[q];
                unsigned rB = u;
                unsigned d = u & 16383u;
                if (d < medge || d >= 16384u - medge) rB = exact_bits(x) | 1u;
                atomicAdd(&sh[(rB >> 14) & 63u], 1u);
                unsigned idx = atomicAdd(cnt, 1u);
                if (idx < CAND_CAP) cand[idx] = x;
            }
        }
    }
    __syncthreads();
    if (threadIdx.x < 64 && sh[threadIdx.x])
        atomicAdd(&ws[H64_OFF + threadIdx.x], sh[threadIdx.x]);
    // flush candidate buffer: one reservation per block
    if (threadIdx.x == 0) {
        unsigned add = (lcnt > LBUF) ? (CAND_CAP + 1u) : lcnt;
        gbase = atomicAdd(cnt, add);
    }
    __syncthreads();
    unsigned c2 = lcnt < LBUF ? lcnt : LBUF;
    for (unsigned q = threadIdx.x; q < c2; q += 256) {
        unsigned gi = gbase + q;
        if (gi < CAND_CAP) cand[gi] = buf[q];
    }
}

// --- k4: select 2^14-wide window ------------------------------------------
__global__ void k4_sel64(unsigned* __restrict__ ws) {
    unsigned* ctrl = ws + CTRL_OFF;
    if (ctrl[0] == 0xFFFFFFFFu) return;
    if (threadIdx.x == 0) {
        long long kprime = (long long)ctrl[1];
        long long cum = 0;
        int s = 0;
        long long kpp = 1;
        for (int j = 63; j >= 0; --j) {
            unsigned v = ws[H64_OFF + j];
            if (cum + (long long)v >= kprime) {
                s = j;
                kpp = kprime - cum;
                break;
            }
            cum += v;
        }
        ctrl[4] = (ctrl[0] << 20) + ((unsigned)s << 14);
        ctrl[5] = (unsigned)kpp;
    }
}

// --- kC: exact histogram over the selected window (candidate-list scan) ---
__global__ __launch_bounds__(256) void kC_histwin(
    const float* __restrict__ lg, const unsigned* __restrict__ ob,
    unsigned* __restrict__ ws, long long n) {
    unsigned wlo = ws[CTRL_OFF + 4];
    if (wlo == 0xFFFFFFFFu) return;
    unsigned whi = wlo + 16384u;
    unsigned medge = ws[CTRL_OFF + 6] + 2u;   // must match kB exactly
    unsigned b12 = ws[CTRL_OFF + 0];
    unsigned lo12 = b12 << 20;
    unsigned hi12 = lo12 + (1u << 20);
    unsigned glo = (wlo - lo12 > medge) ? wlo - medge : lo12;
    unsigned ghi = (hi12 - whi > medge) ? whi + medge : hi12;
    unsigned count = ws[CTRL_OFF + 3];

    long long tid = (long long)blockIdx.x * 256 + threadIdx.x;
    long long stride = (long long)gridDim.x * 256;

    if (count <= CAND_CAP) {
        const float* cand = (const float*)(ws + CAND_OFF);
        for (long long i = tid; i < (long long)count; i += stride) {
            float x = cand[i];
            unsigned u = refine_A(x) | 1u;    // bit-identical to stored bits
            if (u >= glo && u < ghi) {
                unsigned eb = exact_bits(x);  // TRUE untagged bits
                unsigned rB = u;
                unsigned d = u & 16383u;
                if (d < medge || d >= 16384u - medge) rB = eb | 1u;
                if (rB >= wlo && rB < whi) {
                    unsigned off = eb - wlo;
                    if (off < 16384u) atomicAdd(&ws[HC_OFF + off], 1u);
                }
            }
        }
    } else {
        // overflow fallback: rescan full out array (never expected)
        long long n4 = n >> 2;
        const u32x4* o4 = (const u32x4*)ob;
        for (long long i = tid; i < n4; i += stride) {
            u32x4 u4 = o4[i];
            unsigned us[4] = {u4.x, u4.y, u4.z, u4.w};
#pragma unroll
            for (int c = 0; c < 4; ++c) {
                unsigned u = us[c];
                if ((u & 1u) && u != 1u && u >= glo && u < ghi) {
                    float x = lg[i * 4 + c];
                    unsigned eb = exact_bits(x);
                    unsigned rB = u;
                    unsigned d = u & 16383u;
                    if (d < medge || d >= 16384u - medge) rB = eb | 1u;
                    if (rB >= wlo && rB < whi) {
                        unsigned off = eb - wlo;
                        if (off < 16384u) atomicAdd(&ws[HC_OFF + off], 1u);
                    }
                }
            }
        }
        if (tid == 0) {
            for (long long q = (n4 << 2); q < n; ++q) {
                unsigned u = ob[q];
                if ((u & 1u) && u != 1u && u >= glo && u < ghi) {
                    unsigned eb = exact_bits(lg[q]);
                    unsigned rB = u;
                    unsigned d = u & 16383u;
                    if (d < medge || d >= 16384u - medge) rB = eb | 1u;
                    if (rB >= wlo && rB < whi) {
                        unsigned off = eb - wlo;
                        if (off < 16384u) atomicAdd(&ws[HC_OFF + off], 1u);
                    }
                }
            }
        }
    }
}

// --- k6: exact threshold bits from histC ----------------------------------
__global__ __launch_bounds__(1024) void k6_selwin(unsigned* __restrict__ ws) {
    unsigned* ctrl = ws + CTRL_OFF;
    if (ctrl[4] == 0xFFFFFFFFu) return;
    __shared__ unsigned long long csum[1024];
    int t = threadIdx.x;
    unsigned long long s = 0;
    for (int j = 0; j < 16; ++j) s += ws[HC_OFF + t * 16 + j];
    csum[t] = s;
    __syncthreads();
    if (t == 0) {
        long long kpp = (long long)ctrl[5];
        long long cum = 0;
        int sel = 0;
        long long rem = kpp;
        for (int c = 1023; c >= 0; --c) {
            if (cum + (long long)csum[c] >= kpp) {
                sel = c;
                rem = kpp - cum;
                break;
            }
            cum += csum[c];
        }
        long long cc = 0;
        int bsel = 0;
        for (int j = 15; j >= 0; --j) {
            unsigned v = ws[HC_OFF + sel * 16 + j];
            if (cc + (long long)v >= rem) {
                bsel = j;
                break;
            }
            cc += v;
        }
        ctrl[2] = ctrl[4] + (unsigned)(sel * 16 + bsel);
    }
}

// --- kD: final rewrite; knowns final, store vectors ONLY if changed -------
// Regular (cached) loads: ob is L3-resident from kA/kB. No NT anywhere.
__device__ __forceinline__ unsigned kD_elem(unsigned u, unsigned thr,
                                            unsigned mband,
                                            const float* __restrict__ lg,
                                            long long idx, bool* changed) {
    if (!(u & 1u)) return u;                        // known: already final
    unsigned udiff = (u > thr) ? u - thr : thr - u;
    if (udiff <= mband) {                           // banded: exact decision
        unsigned eb = exact_bits(lg[idx]);
        unsigned r = (eb > thr) ? 0u : eb;
        *changed |= (r != u);
        return r;
    }
    if (u > thr) { *changed = true; return 0u; }    // rejected
    return u;                                       // kept (<=1 ulp off, OK)
}

__global__ __launch_bounds__(256) void kD_final(
    const float* __restrict__ lg, unsigned* __restrict__ ob,
    const unsigned* __restrict__ ws, long long n) {
    unsigned thr = ws[CTRL_OFF + 2];
    unsigned mband = ws[CTRL_OFF + 6] + 2u;

    long long n8 = n >> 3;
    long long tid = (long long)blockIdx.x * 256 + threadIdx.x;
    long long stride = (long long)gridDim.x * 256;
    u32x4* o4 = (u32x4*)ob;

    long long i = tid;
    u32x4 ua, ub;
    if (i < n8) {
        ua = o4[2 * i];
        ub = o4[2 * i + 1];
    }
    while (i < n8) {
        long long j = i + stride;
        u32x4 nua, nub;
        if (j < n8) {                       // prefetch next tile
            nua = o4[2 * j];
            nub = o4[2 * j + 1];
        }
        uint4_t: ;
        u32x4 va, vb;
        bool chA = false, chB = false;
        long long base = i * 8;
        va.x = kD_elem(ua.x, thr, mband, lg, base + 0, &chA);
        va.y = kD_elem(ua.y, thr, mband, lg, base + 1, &chA);
        va.z = kD_elem(ua.z, thr, mband, lg, base + 2, &chA);
        va.w = kD_elem(ua.w, thr, mband, lg, base + 3, &chA);
        vb.x = kD_elem(ub.x, thr, mband, lg, base + 4, &chB);
        vb.y = kD_elem(ub.y, thr, mband, lg, base + 5, &chB);
        vb.z = kD_elem(ub.z, thr, mband, lg, base + 6, &chB);
        vb.w = kD_elem(ub.w, thr, mband, lg, base + 7, &chB);
        if (chA) o4[2 * i] = va;
        if (chB) o4[2 * i + 1] = vb;
        ua = nua; ub = nub;
        i = j;
    }
    if (tid == 0) {
        for (long long q = (n >> 3) << 3; q < n; ++q) {
            bool ch = false;
            unsigned r = kD_elem(ob[q], thr, mband, lg, q, &ch);
            if (ch) ob[q] = r;
        }
    }
}

extern "C" void kernel_launch(void* const* d_in, const int* in_sizes, int n_in,
                              void* d_out, int out_size, void* d_ws, size_t ws_size,
                              hipStream_t stream) {
    const float* lg = (const float*)d_in[0];
    const float* tg = (const float*)d_in[1];
    const int* epoch = (const int*)d_in[2];
    float* out = (float*)d_out;
    unsigned* ob = (unsigned*)d_out;
    unsigned* ws = (unsigned*)d_ws;
    long long n = (long long)in_sizes[0];

    (void)hipMemsetAsync(d_ws, 0, (size_t)ZERO_WORDS * 4, stream);

    const int blocks = 2048, threads = 256;
    kA_store_hist<<<blocks, threads, 0, stream>>>(lg, tg, out, ws, n);
    k2_sel12<<<1, 256, 0, stream>>>(ws, epoch);
    kB_hist64<<<blocks, threads, 0, stream>>>(lg, ob, ws, n);
    k4_sel64<<<1, 64, 0, stream>>>(ws);
    kC_histwin<<<1024, threads, 0, stream>>>(lg, ob, ws, n);
    k6_selwin<<<1, 1024, 0, stream>>>(ws);
    kD_final<<<blocks, threads, 0, stream>>>(lg, ob, ws, n);
}

// Round 15
// 216.881 us; speedup vs baseline: 1.3103x; 1.1296x over previous
//
#include <hip/hip_runtime.h>
#include <math.h>

typedef float    f32x4 __attribute__((ext_vector_type(4)));
typedef unsigned u32x4 __attribute__((ext_vector_type(4)));

// ws layout (uint32 words):
//   [0     .. 16384)  histC  (exact low-bits hist over selected 2^14 window)
//   [16384 .. 20480)  hist12 (top-12-bit histogram)
//   [20480 .. 20544)  hist64 (64 sub-bins of width 2^14 within selected b12)
//   [20544 .. 20560)  ctrl: [0]=b12 [1]=kprime [2]=thr_bits [3]=cand_count
//                           [4]=win_lo [5]=kpp [6]=m_bin
//   [20560 .. +CAP)   candidate INDICES (element idx) of selected b12
#define HC_OFF     0u
#define H12_OFF    16384u
#define H64_OFF    20480u
#define CTRL_OFF   20544u
#define ZERO_WORDS 20560u
#define CAND_OFF   20560u
#define CAND_CAP   900000u     // 3.68 MB total (r11/r12 proved 3.70 MB ok)
#define LBUF       2048u

#define FLOOR_BITS 0x36000000u // bits(2^-19): below this, cheap unreliable

// TAGGING (r9/r14-proven): known -> loss_bits & ~1 (even, FINAL);
// unknown -> refined_bits | 1 (odd). <=1-ulp perturbation absorbed by
// margins (+2); 2^20/2^14 bin membership tag-invariant; exact threshold
// bits stay untagged.

// --- exact softplus (UNCHANGED from passing rounds 1-14) -----------------
__device__ __forceinline__ float softplus_exact(float x) {
    float ax = fabsf(x);
    float e = (float)exp(-(double)ax);
    float l = (float)log1p((double)e);
    return fmaxf(x, 0.0f) + l;
}
__device__ __forceinline__ unsigned exact_bits(float x) {
    return __float_as_uint(softplus_exact(x));
}

// --- refinement: cheap + margin-gated exact; DETERMINISTIC fn of x -------
__device__ __forceinline__ unsigned refine_core(float x, float ax, float e,
                                                float sp) {
    unsigned cb = __float_as_uint(sp);
    float mf = 64.0f + 8.0f * ax;
    if (x < 0.0f) mf += __builtin_amdgcn_rcpf(e);
    bool need = (cb < FLOOR_BITS) || (mf >= 524288.0f);
    if (!need) {
        unsigned m = (unsigned)mf;
        unsigned low = cb & 0xFFFFFu;
        need = (low < m) || (low >= 0x100000u - m);
    }
    if (need) cb = exact_bits(x);
    return cb;
}
__device__ __forceinline__ unsigned refine_A(float x) {
    float ax = fabsf(x);
    float e = __expf(-ax);
    float sp = fmaxf(x, 0.0f) + __logf(1.0f + e);
    return refine_core(x, ax, e, sp);
}

// --- kA per-element (r14-proven) ------------------------------------------
__device__ __forceinline__ unsigned kA_elem(float x, float t,
                                            unsigned* __restrict__ sh) {
    float ax = fabsf(x);
    float e = __expf(-ax);
    float sp = fmaxf(x, 0.0f) + __logf(1.0f + e);
    unsigned outb;
    if (isnan(t)) {
        unsigned cb = refine_core(x, ax, e, sp) | 1u;   // tag odd
        if (cb != 1u) atomicAdd(&sh[cb >> 20], 1u);     // count_nonzero
        outb = cb;
    } else {
        float loss = sp - x * t;                    // >= 0 always
        outb = __float_as_uint(loss) & ~1u;         // tag even: FINAL value
    }
    return outb;
}

// --- kA: stream logits+targets; store tagged bits to out; hist12 ---------
__global__ __launch_bounds__(256) void kA_store_hist(
    const float* __restrict__ lg, const float* __restrict__ tg,
    float* __restrict__ out, unsigned* __restrict__ ws, long long n) {
    __shared__ unsigned sh[4096];
    for (int i = threadIdx.x; i < 4096; i += 256) sh[i] = 0;
    __syncthreads();

    long long n8 = n >> 3;
    long long tid = (long long)blockIdx.x * 256 + threadIdx.x;
    long long stride = (long long)gridDim.x * 256;
    const f32x4* lg4 = (const f32x4*)lg;
    const f32x4* tg4 = (const f32x4*)tg;
    f32x4* out4 = (f32x4*)out;

    if (n8 % stride == 0) {
        long long iters = n8 / stride;
        f32x4 xa0, xb0, ta0, tb0, xa1, xb1, ta1, tb1;
        {
            long long i = tid;
            xa0 = lg4[2 * i]; xb0 = lg4[2 * i + 1];
            ta0 = __builtin_nontemporal_load(&tg4[2 * i]);
            tb0 = __builtin_nontemporal_load(&tg4[2 * i + 1]);
        }
        if (iters > 1) {
            long long i = tid + stride;
            xa1 = lg4[2 * i]; xb1 = lg4[2 * i + 1];
            ta1 = __builtin_nontemporal_load(&tg4[2 * i]);
            tb1 = __builtin_nontemporal_load(&tg4[2 * i + 1]);
        }
        for (long long it = 0; it < iters; ++it) {
            f32x4 pa, pb, pta, ptb;
            if (it + 2 < iters) {
                long long i = tid + (it + 2) * stride;
                pa = lg4[2 * i]; pb = lg4[2 * i + 1];
                pta = __builtin_nontemporal_load(&tg4[2 * i]);
                ptb = __builtin_nontemporal_load(&tg4[2 * i + 1]);
            }
            long long i = tid + it * stride;
            f32x4 oa, ob_;
            oa.x = __uint_as_float(kA_elem(xa0.x, ta0.x, sh));
            oa.y = __uint_as_float(kA_elem(xa0.y, ta0.y, sh));
            oa.z = __uint_as_float(kA_elem(xa0.z, ta0.z, sh));
            oa.w = __uint_as_float(kA_elem(xa0.w, ta0.w, sh));
            ob_.x = __uint_as_float(kA_elem(xb0.x, tb0.x, sh));
            ob_.y = __uint_as_float(kA_elem(xb0.y, tb0.y, sh));
            ob_.z = __uint_as_float(kA_elem(xb0.z, tb0.z, sh));
            ob_.w = __uint_as_float(kA_elem(xb0.w, tb0.w, sh));
            out4[2 * i] = oa;
            out4[2 * i + 1] = ob_;
            xa0 = xa1; xb0 = xb1; ta0 = ta1; tb0 = tb1;
            xa1 = pa; xb1 = pb; ta1 = pta; tb1 = ptb;
        }
    } else {
        for (long long i = tid; i < n8; i += stride) {
            f32x4 xa = lg4[2 * i], xb = lg4[2 * i + 1];
            f32x4 ta = tg4[2 * i], tb = tg4[2 * i + 1];
            f32x4 oa, ob_;
            oa.x = __uint_as_float(kA_elem(xa.x, ta.x, sh));
            oa.y = __uint_as_float(kA_elem(xa.y, ta.y, sh));
            oa.z = __uint_as_float(kA_elem(xa.z, ta.z, sh));
            oa.w = __uint_as_float(kA_elem(xa.w, ta.w, sh));
            ob_.x = __uint_as_float(kA_elem(xb.x, tb.x, sh));
            ob_.y = __uint_as_float(kA_elem(xb.y, tb.y, sh));
            ob_.z = __uint_as_float(kA_elem(xb.z, tb.z, sh));
            ob_.w = __uint_as_float(kA_elem(xb.w, tb.w, sh));
            out4[2 * i] = oa;
            out4[2 * i + 1] = ob_;
        }
    }
    if (tid == 0) {   // scalar tail
        for (long long q = (n >> 3) << 3; q < n; ++q)
            out[q] = __uint_as_float(kA_elem(lg[q], tg[q], sh));
    }
    __syncthreads();
    unsigned* hist12 = ws + H12_OFF;
    for (int q = threadIdx.x; q < 4096; q += 256)
        if (sh[q]) atomicAdd(&hist12[q], sh[q]);
}

// --- k2: select 12-bit bin; compute k, kprime, and bin-wide margin -------
__global__ __launch_bounds__(256) void k2_sel12(
    unsigned* __restrict__ ws, const int* __restrict__ epoch_ptr) {
    const unsigned* hist12 = ws + H12_OFF;
    unsigned* ctrl = ws + CTRL_OFF;
    __shared__ unsigned long long chunk[256];
    int t = threadIdx.x;
    unsigned long long s = 0;
    for (int j = 0; j < 16; ++j) s += hist12[t * 16 + j];
    chunk[t] = s;
    __syncthreads();
    if (t == 0) {
        unsigned long long tot = 0;
        for (int c = 0; c < 256; ++c) tot += chunk[c];
        int epoch = epoch_ptr[0];
        float percent = fminf((float)epoch * 0.1f, 1.0f);
        float nf = (float)tot;              // astype(float32)
        float kr = rintf(nf * percent);     // jnp.round half-to-even
        long long k = (long long)kr;        // astype(int32)
        if (k < 1) k = 1;

        long long cum = 0;
        int b = -1;
        long long kprime = 0;
        for (int c = 255; c >= 0; --c) {
            if (cum + (long long)chunk[c] >= k) {
                long long cc = cum;
                for (int j = 15; j >= 0; --j) {
                    unsigned v = hist12[c * 16 + j];
                    if (cc + (long long)v >= k) {
                        b = c * 16 + j;
                        kprime = k - cc;
                        break;
                    }
                    cc += v;
                }
                break;
            }
            cum += chunk[c];
        }
        ctrl[0] = (unsigned)b;
        ctrl[1] = (unsigned)kprime;
        if (b < 0) {
            ctrl[2] = 0u;                   // threshold = 0.0f
            ctrl[4] = 0xFFFFFFFFu;          // no window
            ctrl[6] = 0u;
        } else {
            unsigned lo12 = (unsigned)b << 20;
            double vlo = (double)__uint_as_float(lo12);
            double vhi = (double)__uint_as_float(lo12 + 0xFFFFFu);
            double mb = 1e9;
            if (vlo > 1e-30) {
                double xlo = vlo + log1p(-exp(-vlo)) - 0.001;  // inv_softplus
                double xhi = vhi + log1p(-exp(-vhi)) + 0.001;
                double axmax = fmax(fabs(xlo), fabs(xhi));
                mb = 64.0 + 8.0 * ceil(axmax);
                if (xlo < 0.0) mb += exp(fmin(-xlo, 30.0));
                mb *= 2.0;                  // safety factor
            }
            ctrl[6] = (mb >= 8192.0) ? 8192u : (unsigned)mb;
        }
    }
}

// --- kB: zero definite rejects (u >= hi12), hist64 + compact candidate idx
// refine_core is EXACT within m of every 2^20 edge, so the u >= hi12 test
// agrees with exact bits: eb >= hi12 > thr -> reject is final.
__global__ __launch_bounds__(256) void kB_zero(
    const float* __restrict__ lg, unsigned* __restrict__ ob,
    unsigned* __restrict__ ws, long long n) {
    unsigned b12 = ws[CTRL_OFF + 0];
    if (b12 == 0xFFFFFFFFu) return;
    unsigned lo12 = b12 << 20;
    unsigned hi12 = (b12 >= 4095u) ? 0xFFFFFFFFu : (lo12 + (1u << 20));
    unsigned medge = ws[CTRL_OFF + 6] + 2u;   // +2: tag absorption

    __shared__ unsigned sh[64];
    __shared__ unsigned buf[LBUF];
    __shared__ unsigned lcnt, gbase;
    if (threadIdx.x < 64) sh[threadIdx.x] = 0;
    if (threadIdx.x == 0) lcnt = 0;
    __syncthreads();

    unsigned* cand = ws + CAND_OFF;
    unsigned* cnt = ws + CTRL_OFF + 3;

    long long n4 = n >> 2;
    long long tid = (long long)blockIdx.x * 256 + threadIdx.x;
    long long stride = (long long)gridDim.x * 256;
    u32x4* o4 = (u32x4*)ob;

    long long i = tid;
    u32x4 u4;
    if (i < n4) u4 = o4[i];
    while (i < n4) {
        long long j = i + stride;
        u32x4 nu4;
        if (j < n4) nu4 = o4[j];            // prefetch next tile
        unsigned us[4] = {u4.x, u4.y, u4.z, u4.w};
#pragma unroll
        for (int c = 0; c < 4; ++c) {
            unsigned u = us[c];
            if ((u & 1u) && u != 1u) {      // unknown, nonzero loss
                if (u >= hi12) {
                    ob[i * 4 + c] = 0u;     // definite reject: final zero
                } else if (u >= lo12) {     // candidate
                    unsigned rB = u;
                    unsigned d = u & 16383u;
                    if (d < medge || d >= 16384u - medge)
                        rB = exact_bits(lg[i * 4 + c]) | 1u;  // edge: exact
                    atomicAdd(&sh[(rB >> 14) & 63u], 1u);
                    unsigned li = atomicAdd(&lcnt, 1u);
                    if (li < LBUF) buf[li] = (unsigned)(i * 4 + c);
                }
            }
        }
        u4 = nu4;
        i = j;
    }
    if (tid == 0) {  // scalar tail (empty for n % 4 == 0): direct append
        for (long long q = (n4 << 2); q < n; ++q) {
            unsigned u = ob[q];
            if ((u & 1u) && u != 1u) {
                if (u >= hi12) {
                    ob[q] = 0u;
                } else if (u >= lo12) {
                    unsigned rB = u;
                    unsigned d = u & 16383u;
                    if (d < medge || d >= 16384u - medge)
                        rB = exact_bits(lg[q]) | 1u;
                    atomicAdd(&sh[(rB >> 14) & 63u], 1u);
                    unsigned idx = atomicAdd(cnt, 1u);
                    if (idx < CAND_CAP) cand[idx] = (unsigned)q;
                }
            }
        }
    }
    __syncthreads();
    if (threadIdx.x < 64 && sh[threadIdx.x])
        atomicAdd(&ws[H64_OFF + threadIdx.x], sh[threadIdx.x]);
    if (threadIdx.x == 0) {
        // on LDS overflow, poison count -> kC/kD take full-scan fallback
        unsigned add = (lcnt > LBUF) ? (CAND_CAP + 1u) : lcnt;
        gbase = atomicAdd(cnt, add);
    }
    __syncthreads();
    unsigned c2 = lcnt < LBUF ? lcnt : LBUF;
    for (unsigned q = threadIdx.x; q < c2; q += 256) {
        unsigned gi = gbase + q;
        if (gi < CAND_CAP) cand[gi] = buf[q];
    }
}

// --- k4: select 2^14-wide window ------------------------------------------
__global__ void k4_sel64(unsigned* __restrict__ ws) {
    unsigned* ctrl = ws + CTRL_OFF;
    if (ctrl[0] == 0xFFFFFFFFu) return;
    if (threadIdx.x == 0) {
        long long kprime = (long long)ctrl[1];
        long long cum = 0;
        int s = 0;
        long long kpp = 1;
        for (int j = 63; j >= 0; --j) {
            unsigned v = ws[H64_OFF + j];
            if (cum + (long long)v >= kprime) {
                s = j;
                kpp = kprime - cum;
                break;
            }
            cum += v;
        }
        ctrl[4] = (ctrl[0] << 20) + ((unsigned)s << 14);
        ctrl[5] = (unsigned)kpp;
    }
}

// --- kC: exact histogram over the selected window (idx-list scan) ---------
__global__ __launch_bounds__(256) void kC_histwin(
    const float* __restrict__ lg, const unsigned* __restrict__ ob,
    unsigned* __restrict__ ws, long long n) {
    unsigned wlo = ws[CTRL_OFF + 4];
    if (wlo == 0xFFFFFFFFu) return;
    unsigned whi = wlo + 16384u;
    unsigned medge = ws[CTRL_OFF + 6] + 2u;   // must match kB exactly
    unsigned b12 = ws[CTRL_OFF + 0];
    unsigned lo12 = b12 << 20;
    unsigned hi12 = (b12 >= 4095u) ? 0xFFFFFFFFu : (lo12 + (1u << 20));
    unsigned glo = (wlo - lo12 > medge) ? wlo - medge : lo12;
    unsigned ghi = (hi12 - whi > medge) ? whi + medge : hi12;
    unsigned count = ws[CTRL_OFF + 3];

    long long tid = (long long)blockIdx.x * 256 + threadIdx.x;
    long long stride = (long long)gridDim.x * 256;

    if (count <= CAND_CAP) {
        const unsigned* cand = ws + CAND_OFF;
        for (long long i = tid; i < (long long)count; i += stride) {
            unsigned idx = cand[i];
            float x = lg[idx];
            unsigned u = refine_A(x) | 1u;    // bit-identical to stored bits
            if (u >= glo && u < ghi) {
                unsigned eb = exact_bits(x);  // TRUE untagged bits
                unsigned rB = u;
                unsigned d = u & 16383u;
                if (d < medge || d >= 16384u - medge) rB = eb | 1u;
                if (rB >= wlo && rB < whi) {
                    unsigned off = eb - wlo;
                    if (off < 16384u) atomicAdd(&ws[HC_OFF + off], 1u);
                }
            }
        }
    } else {
        // overflow fallback: rescan full out array (never expected)
        long long n4 = n >> 2;
        const u32x4* o4 = (const u32x4*)ob;
        for (long long i = tid; i < n4; i += stride) {
            u32x4 u4 = o4[i];
            unsigned us[4] = {u4.x, u4.y, u4.z, u4.w};
#pragma unroll
            for (int c = 0; c < 4; ++c) {
                unsigned u = us[c];
                if ((u & 1u) && u != 1u && u >= glo && u < ghi) {
                    float x = lg[i * 4 + c];
                    unsigned eb = exact_bits(x);
                    unsigned rB = u;
                    unsigned d = u & 16383u;
                    if (d < medge || d >= 16384u - medge) rB = eb | 1u;
                    if (rB >= wlo && rB < whi) {
                        unsigned off = eb - wlo;
                        if (off < 16384u) atomicAdd(&ws[HC_OFF + off], 1u);
                    }
                }
            }
        }
        if (tid == 0) {
            for (long long q = (n4 << 2); q < n; ++q) {
                unsigned u = ob[q];
                if ((u & 1u) && u != 1u && u >= glo && u < ghi) {
                    unsigned eb = exact_bits(lg[q]);
                    unsigned rB = u;
                    unsigned d = u & 16383u;
                    if (d < medge || d >= 16384u - medge) rB = eb | 1u;
                    if (rB >= wlo && rB < whi) {
                        unsigned off = eb - wlo;
                        if (off < 16384u) atomicAdd(&ws[HC_OFF + off], 1u);
                    }
                }
            }
        }
    }
}

// --- k6: exact threshold bits from histC ----------------------------------
__global__ __launch_bounds__(1024) void k6_selwin(unsigned* __restrict__ ws) {
    unsigned* ctrl = ws + CTRL_OFF;
    if (ctrl[4] == 0xFFFFFFFFu) return;
    __shared__ unsigned long long csum[1024];
    int t = threadIdx.x;
    unsigned long long s = 0;
    for (int j = 0; j < 16; ++j) s += ws[HC_OFF + t * 16 + j];
    csum[t] = s;
    __syncthreads();
    if (t == 0) {
        long long kpp = (long long)ctrl[5];
        long long cum = 0;
        int sel = 0;
        long long rem = kpp;
        for (int c = 1023; c >= 0; --c) {
            if (cum + (long long)csum[c] >= kpp) {
                sel = c;
                rem = kpp - cum;
                break;
            }
            cum += csum[c];
        }
        long long cc = 0;
        int bsel = 0;
        for (int j = 15; j >= 0; --j) {
            unsigned v = ws[HC_OFF + sel * 16 + j];
            if (cc + (long long)v >= rem) {
                bsel = j;
                break;
            }
            cc += v;
        }
        ctrl[2] = ctrl[4] + (unsigned)(sel * 16 + bsel);
    }
}

// --- kD_cand: fixup ONLY the candidates (main path) ------------------------
__global__ __launch_bounds__(256) void kD_cand(
    const float* __restrict__ lg, unsigned* __restrict__ ob,
    const unsigned* __restrict__ ws) {
    unsigned count = ws[CTRL_OFF + 3];
    if (count > CAND_CAP) return;           // fallback kernel handles it
    unsigned thr = ws[CTRL_OFF + 2];
    unsigned mband = ws[CTRL_OFF + 6] + 2u;
    const unsigned* cand = ws + CAND_OFF;

    long long tid = (long long)blockIdx.x * 256 + threadIdx.x;
    long long stride = (long long)gridDim.x * 256;
    for (long long i = tid; i < (long long)count; i += stride) {
        unsigned idx = cand[i];
        unsigned u = ob[idx];
        unsigned udiff = (u > thr) ? u - thr : thr - u;
        if (udiff <= mband) {               // banded: exact decision
            unsigned eb = exact_bits(lg[idx]);
            if (eb > thr) ob[idx] = 0u;
        } else if (u > thr) {
            ob[idx] = 0u;                   // rejected
        }
        // kept: tagged value stays (<=2 ulp off true loss, bf16 absorbs)
    }
}

// --- kD_full: fallback full-array rewrite (cand overflow only) -------------
__device__ __forceinline__ unsigned kD_elem(unsigned u, unsigned thr,
                                            unsigned mband,
                                            const float* __restrict__ lg,
                                            long long idx, bool* changed) {
    if (!(u & 1u)) return u;                        // known/zero: final
    unsigned udiff = (u > thr) ? u - thr : thr - u;
    if (udiff <= mband) {
        unsigned eb = exact_bits(lg[idx]);
        unsigned r = (eb > thr) ? 0u : eb;
        *changed |= (r != u);
        return r;
    }
    if (u > thr) { *changed = true; return 0u; }
    return u;
}

__global__ __launch_bounds__(256) void kD_full(
    const float* __restrict__ lg, unsigned* __restrict__ ob,
    const unsigned* __restrict__ ws, long long n) {
    if (ws[CTRL_OFF + 3] <= CAND_CAP) return;       // main path handled it
    unsigned thr = ws[CTRL_OFF + 2];
    unsigned mband = ws[CTRL_OFF + 6] + 2u;

    long long n8 = n >> 3;
    long long tid = (long long)blockIdx.x * 256 + threadIdx.x;
    long long stride = (long long)gridDim.x * 256;
    u32x4* o4 = (u32x4*)ob;

    for (long long i = tid; i < n8; i += stride) {
        u32x4 ua = o4[2 * i];
        u32x4 ub = o4[2 * i + 1];
        u32x4 va, vb;
        bool chA = false, chB = false;
        long long base = i * 8;
        va.x = kD_elem(ua.x, thr, mband, lg, base + 0, &chA);
        va.y = kD_elem(ua.y, thr, mband, lg, base + 1, &chA);
        va.z = kD_elem(ua.z, thr, mband, lg, base + 2, &chA);
        va.w = kD_elem(ua.w, thr, mband, lg, base + 3, &chA);
        vb.x = kD_elem(ub.x, thr, mband, lg, base + 4, &chB);
        vb.y = kD_elem(ub.y, thr, mband, lg, base + 5, &chB);
        vb.z = kD_elem(ub.z, thr, mband, lg, base + 6, &chB);
        vb.w = kD_elem(ub.w, thr, mband, lg, base + 7, &chB);
        if (chA) o4[2 * i] = va;
        if (chB) o4[2 * i + 1] = vb;
    }
    if (tid == 0) {
        for (long long q = (n >> 3) << 3; q < n; ++q) {
            bool ch = false;
            unsigned r = kD_elem(ob[q], thr, mband, lg, q, &ch);
            if (ch) ob[q] = r;
        }
    }
}

extern "C" void kernel_launch(void* const* d_in, const int* in_sizes, int n_in,
                              void* d_out, int out_size, void* d_ws, size_t ws_size,
                              hipStream_t stream) {
    const float* lg = (const float*)d_in[0];
    const float* tg = (const float*)d_in[1];
    const int* epoch = (const int*)d_in[2];
    float* out = (float*)d_out;
    unsigned* ob = (unsigned*)d_out;
    unsigned* ws = (unsigned*)d_ws;
    long long n = (long long)in_sizes[0];

    (void)hipMemsetAsync(d_ws, 0, (size_t)ZERO_WORDS * 4, stream);

    const int blocks = 2048, threads = 256;
    kA_store_hist<<<blocks, threads, 0, stream>>>(lg, tg, out, ws, n);
    k2_sel12<<<1, 256, 0, stream>>>(ws, epoch);
    kB_zero<<<blocks, threads, 0, stream>>>(lg, ob, ws, n);
    k4_sel64<<<1, 64, 0, stream>>>(ws);
    kC_histwin<<<1024, threads, 0, stream>>>(lg, ob, ws, n);
    k6_selwin<<<1, 1024, 0, stream>>>(ws);
    kD_cand<<<256, threads, 0, stream>>>(lg, ob, ws);
    kD_full<<<blocks, threads, 0, stream>>>(lg, ob, ws, n);
}

// Round 16
// 214.616 us; speedup vs baseline: 1.3241x; 1.0106x over previous
//
#include <hip/hip_runtime.h>
#include <math.h>

typedef float    f32x4 __attribute__((ext_vector_type(4)));
typedef unsigned u32x4 __attribute__((ext_vector_type(4)));

// ws layout (uint32 words):
//   [0     .. 16384)  histC  (exact low-bits hist over selected 2^14 window)
//   [16384 .. 20480)  hist12 (top-12-bit histogram)
//   [20480 .. 20544)  hist64 (64 sub-bins of width 2^14 within selected b12)
//   [20544 .. 20560)  ctrl: [0]=b12 [1]=kprime [2]=thr_bits [3]=cand_count
//                           [4]=win_lo [5]=kpp [6]=m_bin
//   [20560 .. +CAP)   candidate INDICES (element idx) of selected b12
#define HC_OFF     0u
#define H12_OFF    16384u
#define H64_OFF    20480u
#define CTRL_OFF   20544u
#define ZERO_WORDS 20560u
#define CAND_OFF   20560u
#define CAND_CAP   900000u
#define LBUF       2048u

#define FLOOR_BITS 0x36000000u // bits(2^-19): below this, cheap unreliable

// TAGGING (r9/r14/r15-proven): known -> loss_bits & ~1 (even, FINAL);
// unknown -> refined_bits | 1 (odd). <=1-ulp perturbation absorbed by
// margins (+2); 2^20/2^14 bin membership tag-invariant; exact threshold
// bits stay untagged.

// --- exact softplus (UNCHANGED from passing rounds 1-15) -----------------
__device__ __forceinline__ float softplus_exact(float x) {
    float ax = fabsf(x);
    float e = (float)exp(-(double)ax);
    float l = (float)log1p((double)e);
    return fmaxf(x, 0.0f) + l;
}
__device__ __forceinline__ unsigned exact_bits(float x) {
    return __float_as_uint(softplus_exact(x));
}

// --- refinement: cheap + margin-gated exact; DETERMINISTIC fn of x -------
__device__ __forceinline__ unsigned refine_core(float x, float ax, float e,
                                                float sp) {
    unsigned cb = __float_as_uint(sp);
    float mf = 64.0f + 8.0f * ax;
    if (x < 0.0f) mf += __builtin_amdgcn_rcpf(e);
    bool need = (cb < FLOOR_BITS) || (mf >= 524288.0f);
    if (!need) {
        unsigned m = (unsigned)mf;
        unsigned low = cb & 0xFFFFFu;
        need = (low < m) || (low >= 0x100000u - m);
    }
    if (need) cb = exact_bits(x);
    return cb;
}
__device__ __forceinline__ unsigned refine_A(float x) {
    float ax = fabsf(x);
    float e = __expf(-ax);
    float sp = fmaxf(x, 0.0f) + __logf(1.0f + e);
    return refine_core(x, ax, e, sp);
}

// --- kA per-element (r14/r15-proven) --------------------------------------
__device__ __forceinline__ unsigned kA_elem(float x, float t,
                                            unsigned* __restrict__ sh) {
    float ax = fabsf(x);
    float e = __expf(-ax);
    float sp = fmaxf(x, 0.0f) + __logf(1.0f + e);
    unsigned outb;
    if (isnan(t)) {
        unsigned cb = refine_core(x, ax, e, sp) | 1u;   // tag odd
        if (cb != 1u) atomicAdd(&sh[cb >> 20], 1u);     // count_nonzero
        outb = cb;
    } else {
        float loss = sp - x * t;                    // >= 0 always
        outb = __float_as_uint(loss) & ~1u;         // tag even: FINAL value
    }
    return outb;
}

// --- kA: stream logits+targets; store tagged bits to out; hist12 ---------
__global__ __launch_bounds__(256) void kA_store_hist(
    const float* __restrict__ lg, const float* __restrict__ tg,
    float* __restrict__ out, unsigned* __restrict__ ws, long long n) {
    __shared__ unsigned sh[4096];
    for (int i = threadIdx.x; i < 4096; i += 256) sh[i] = 0;
    __syncthreads();

    long long n8 = n >> 3;
    long long tid = (long long)blockIdx.x * 256 + threadIdx.x;
    long long stride = (long long)gridDim.x * 256;
    const f32x4* lg4 = (const f32x4*)lg;
    const f32x4* tg4 = (const f32x4*)tg;
    f32x4* out4 = (f32x4*)out;

    if (n8 % stride == 0) {
        long long iters = n8 / stride;
        f32x4 xa0, xb0, ta0, tb0, xa1, xb1, ta1, tb1;
        {
            long long i = tid;
            xa0 = lg4[2 * i]; xb0 = lg4[2 * i + 1];
            ta0 = __builtin_nontemporal_load(&tg4[2 * i]);
            tb0 = __builtin_nontemporal_load(&tg4[2 * i + 1]);
        }
        if (iters > 1) {
            long long i = tid + stride;
            xa1 = lg4[2 * i]; xb1 = lg4[2 * i + 1];
            ta1 = __builtin_nontemporal_load(&tg4[2 * i]);
            tb1 = __builtin_nontemporal_load(&tg4[2 * i + 1]);
        }
        for (long long it = 0; it < iters; ++it) {
            f32x4 pa, pb, pta, ptb;
            if (it + 2 < iters) {
                long long i = tid + (it + 2) * stride;
                pa = lg4[2 * i]; pb = lg4[2 * i + 1];
                pta = __builtin_nontemporal_load(&tg4[2 * i]);
                ptb = __builtin_nontemporal_load(&tg4[2 * i + 1]);
            }
            long long i = tid + it * stride;
            f32x4 oa, ob_;
            oa.x = __uint_as_float(kA_elem(xa0.x, ta0.x, sh));
            oa.y = __uint_as_float(kA_elem(xa0.y, ta0.y, sh));
            oa.z = __uint_as_float(kA_elem(xa0.z, ta0.z, sh));
            oa.w = __uint_as_float(kA_elem(xa0.w, ta0.w, sh));
            ob_.x = __uint_as_float(kA_elem(xb0.x, tb0.x, sh));
            ob_.y = __uint_as_float(kA_elem(xb0.y, tb0.y, sh));
            ob_.z = __uint_as_float(kA_elem(xb0.z, tb0.z, sh));
            ob_.w = __uint_as_float(kA_elem(xb0.w, tb0.w, sh));
            out4[2 * i] = oa;
            out4[2 * i + 1] = ob_;
            xa0 = xa1; xb0 = xb1; ta0 = ta1; tb0 = tb1;
            xa1 = pa; xb1 = pb; ta1 = pta; tb1 = ptb;
        }
    } else {
        for (long long i = tid; i < n8; i += stride) {
            f32x4 xa = lg4[2 * i], xb = lg4[2 * i + 1];
            f32x4 ta = tg4[2 * i], tb = tg4[2 * i + 1];
            f32x4 oa, ob_;
            oa.x = __uint_as_float(kA_elem(xa.x, ta.x, sh));
            oa.y = __uint_as_float(kA_elem(xa.y, ta.y, sh));
            oa.z = __uint_as_float(kA_elem(xa.z, ta.z, sh));
            oa.w = __uint_as_float(kA_elem(xa.w, ta.w, sh));
            ob_.x = __uint_as_float(kA_elem(xb.x, tb.x, sh));
            ob_.y = __uint_as_float(kA_elem(xb.y, tb.y, sh));
            ob_.z = __uint_as_float(kA_elem(xb.z, tb.z, sh));
            ob_.w = __uint_as_float(kA_elem(xb.w, tb.w, sh));
            out4[2 * i] = oa;
            out4[2 * i + 1] = ob_;
        }
    }
    if (tid == 0) {   // scalar tail
        for (long long q = (n >> 3) << 3; q < n; ++q)
            out[q] = __uint_as_float(kA_elem(lg[q], tg[q], sh));
    }
    __syncthreads();
    unsigned* hist12 = ws + H12_OFF;
    for (int q = threadIdx.x; q < 4096; q += 256)
        if (sh[q]) atomicAdd(&hist12[q], sh[q]);
}

// --- k2: select 12-bit bin; compute k, kprime, and bin-wide margin -------
__global__ __launch_bounds__(256) void k2_sel12(
    unsigned* __restrict__ ws, const int* __restrict__ epoch_ptr) {
    const unsigned* hist12 = ws + H12_OFF;
    unsigned* ctrl = ws + CTRL_OFF;
    __shared__ unsigned long long chunk[256];
    int t = threadIdx.x;
    unsigned long long s = 0;
    for (int j = 0; j < 16; ++j) s += hist12[t * 16 + j];
    chunk[t] = s;
    __syncthreads();
    if (t == 0) {
        unsigned long long tot = 0;
        for (int c = 0; c < 256; ++c) tot += chunk[c];
        int epoch = epoch_ptr[0];
        float percent = fminf((float)epoch * 0.1f, 1.0f);
        float nf = (float)tot;              // astype(float32)
        float kr = rintf(nf * percent);     // jnp.round half-to-even
        long long k = (long long)kr;        // astype(int32)
        if (k < 1) k = 1;

        long long cum = 0;
        int b = -1;
        long long kprime = 0;
        for (int c = 255; c >= 0; --c) {
            if (cum + (long long)chunk[c] >= k) {
                long long cc = cum;
                for (int j = 15; j >= 0; --j) {
                    unsigned v = hist12[c * 16 + j];
                    if (cc + (long long)v >= k) {
                        b = c * 16 + j;
                        kprime = k - cc;
                        break;
                    }
                    cc += v;
                }
                break;
            }
            cum += chunk[c];
        }
        ctrl[0] = (unsigned)b;
        ctrl[1] = (unsigned)kprime;
        if (b < 0) {
            ctrl[2] = 0u;                   // threshold = 0.0f
            ctrl[4] = 0xFFFFFFFFu;          // no window
            ctrl[6] = 0u;
        } else {
            unsigned lo12 = (unsigned)b << 20;
            double vlo = (double)__uint_as_float(lo12);
            double vhi = (double)__uint_as_float(lo12 + 0xFFFFFu);
            double mb = 1e9;
            if (vlo > 1e-30) {
                double xlo = vlo + log1p(-exp(-vlo)) - 0.001;  // inv_softplus
                double xhi = vhi + log1p(-exp(-vhi)) + 0.001;
                double axmax = fmax(fabs(xlo), fabs(xhi));
                mb = 64.0 + 8.0 * ceil(axmax);
                if (xlo < 0.0) mb += exp(fmin(-xlo, 30.0));
                mb *= 2.0;                  // safety factor
            }
            ctrl[6] = (mb >= 8192.0) ? 8192u : (unsigned)mb;
        }
    }
}

// --- kB: zero definite rejects (u >= hi12), hist64 + compact candidate idx
// 8-elem/iter depth-2 pipeline (kA's proven loop shape).
__device__ __forceinline__ void kB_elem(unsigned u, long long idx,
                                        unsigned lo12, unsigned hi12,
                                        unsigned medge,
                                        const float* __restrict__ lg,
                                        unsigned* __restrict__ ob,
                                        unsigned* __restrict__ sh,
                                        unsigned* __restrict__ buf,
                                        unsigned* __restrict__ lcnt) {
    if ((u & 1u) && u != 1u) {          // unknown, nonzero loss
        if (u >= hi12) {
            ob[idx] = 0u;               // definite reject: final zero
        } else if (u >= lo12) {         // candidate
            unsigned rB = u;
            unsigned d = u & 16383u;
            if (d < medge || d >= 16384u - medge)
                rB = exact_bits(lg[idx]) | 1u;   // edge: exact (tagged bin)
            atomicAdd(&sh[(rB >> 14) & 63u], 1u);
            unsigned li = atomicAdd(lcnt, 1u);
            if (li < LBUF) buf[li] = (unsigned)idx;
        }
    }
}

__global__ __launch_bounds__(256) void kB_zero(
    const float* __restrict__ lg, unsigned* __restrict__ ob,
    unsigned* __restrict__ ws, long long n) {
    unsigned b12 = ws[CTRL_OFF + 0];
    if (b12 == 0xFFFFFFFFu) return;
    unsigned lo12 = b12 << 20;
    unsigned hi12 = (b12 >= 4095u) ? 0xFFFFFFFFu : (lo12 + (1u << 20));
    unsigned medge = ws[CTRL_OFF + 6] + 2u;   // +2: tag absorption

    __shared__ unsigned sh[64];
    __shared__ unsigned buf[LBUF];
    __shared__ unsigned lcnt, gbase;
    if (threadIdx.x < 64) sh[threadIdx.x] = 0;
    if (threadIdx.x == 0) lcnt = 0;
    __syncthreads();

    unsigned* cand = ws + CAND_OFF;
    unsigned* cnt = ws + CTRL_OFF + 3;

    long long n8 = n >> 3;
    long long tid = (long long)blockIdx.x * 256 + threadIdx.x;
    long long stride = (long long)gridDim.x * 256;
    const u32x4* o4 = (const u32x4*)ob;

    if (n8 % stride == 0) {
        long long iters = n8 / stride;
        u32x4 ua0, ub0, ua1, ub1;
        {
            long long i = tid;
            ua0 = o4[2 * i]; ub0 = o4[2 * i + 1];
        }
        if (iters > 1) {
            long long i = tid + stride;
            ua1 = o4[2 * i]; ub1 = o4[2 * i + 1];
        }
        for (long long it = 0; it < iters; ++it) {
            u32x4 pa, pb;
            if (it + 2 < iters) {
                long long i = tid + (it + 2) * stride;
                pa = o4[2 * i]; pb = o4[2 * i + 1];
            }
            long long i = tid + it * stride;
            long long base = i * 8;
            kB_elem(ua0.x, base + 0, lo12, hi12, medge, lg, ob, sh, buf, &lcnt);
            kB_elem(ua0.y, base + 1, lo12, hi12, medge, lg, ob, sh, buf, &lcnt);
            kB_elem(ua0.z, base + 2, lo12, hi12, medge, lg, ob, sh, buf, &lcnt);
            kB_elem(ua0.w, base + 3, lo12, hi12, medge, lg, ob, sh, buf, &lcnt);
            kB_elem(ub0.x, base + 4, lo12, hi12, medge, lg, ob, sh, buf, &lcnt);
            kB_elem(ub0.y, base + 5, lo12, hi12, medge, lg, ob, sh, buf, &lcnt);
            kB_elem(ub0.z, base + 6, lo12, hi12, medge, lg, ob, sh, buf, &lcnt);
            kB_elem(ub0.w, base + 7, lo12, hi12, medge, lg, ob, sh, buf, &lcnt);
            ua0 = ua1; ub0 = ub1;
            ua1 = pa; ub1 = pb;
        }
    } else {
        for (long long i = tid; i < n8; i += stride) {
            u32x4 ua = o4[2 * i], ub = o4[2 * i + 1];
            long long base = i * 8;
            kB_elem(ua.x, base + 0, lo12, hi12, medge, lg, ob, sh, buf, &lcnt);
            kB_elem(ua.y, base + 1, lo12, hi12, medge, lg, ob, sh, buf, &lcnt);
            kB_elem(ua.z, base + 2, lo12, hi12, medge, lg, ob, sh, buf, &lcnt);
            kB_elem(ua.w, base + 3, lo12, hi12, medge, lg, ob, sh, buf, &lcnt);
            kB_elem(ub.x, base + 4, lo12, hi12, medge, lg, ob, sh, buf, &lcnt);
            kB_elem(ub.y, base + 5, lo12, hi12, medge, lg, ob, sh, buf, &lcnt);
            kB_elem(ub.z, base + 6, lo12, hi12, medge, lg, ob, sh, buf, &lcnt);
            kB_elem(ub.w, base + 7, lo12, hi12, medge, lg, ob, sh, buf, &lcnt);
        }
    }
    if (tid == 0) {   // scalar tail
        for (long long q = (n >> 3) << 3; q < n; ++q)
            kB_elem(ob[q], q, lo12, hi12, medge, lg, ob, sh, buf, &lcnt);
    }
    __syncthreads();
    if (threadIdx.x < 64 && sh[threadIdx.x])
        atomicAdd(&ws[H64_OFF + threadIdx.x], sh[threadIdx.x]);
    if (threadIdx.x == 0) {
        // on LDS overflow, poison count -> kC/kD take full-scan fallback
        unsigned add = (lcnt > LBUF) ? (CAND_CAP + 1u) : lcnt;
        gbase = atomicAdd(cnt, add);
    }
    __syncthreads();
    unsigned c2 = lcnt < LBUF ? lcnt : LBUF;
    for (unsigned q = threadIdx.x; q < c2; q += 256) {
        unsigned gi = gbase + q;
        if (gi < CAND_CAP) cand[gi] = buf[q];
    }
}

// --- k4: select 2^14-wide window ------------------------------------------
__global__ void k4_sel64(unsigned* __restrict__ ws) {
    unsigned* ctrl = ws + CTRL_OFF;
    if (ctrl[0] == 0xFFFFFFFFu) return;
    if (threadIdx.x == 0) {
        long long kprime = (long long)ctrl[1];
        long long cum = 0;
        int s = 0;
        long long kpp = 1;
        for (int j = 63; j >= 0; --j) {
            unsigned v = ws[H64_OFF + j];
            if (cum + (long long)v >= kprime) {
                s = j;
                kpp = kprime - cum;
                break;
            }
            cum += v;
        }
        ctrl[4] = (ctrl[0] << 20) + ((unsigned)s << 14);
        ctrl[5] = (unsigned)kpp;
    }
}

// --- kC: exact histogram over the selected window (idx-list scan) ---------
__global__ __launch_bounds__(256) void kC_histwin(
    const float* __restrict__ lg, const unsigned* __restrict__ ob,
    unsigned* __restrict__ ws, long long n) {
    unsigned wlo = ws[CTRL_OFF + 4];
    if (wlo == 0xFFFFFFFFu) return;
    unsigned whi = wlo + 16384u;
    unsigned medge = ws[CTRL_OFF + 6] + 2u;   // must match kB exactly
    unsigned b12 = ws[CTRL_OFF + 0];
    unsigned lo12 = b12 << 20;
    unsigned hi12 = (b12 >= 4095u) ? 0xFFFFFFFFu : (lo12 + (1u << 20));
    unsigned glo = (wlo - lo12 > medge) ? wlo - medge : lo12;
    unsigned ghi = (hi12 - whi > medge) ? whi + medge : hi12;
    unsigned count = ws[CTRL_OFF + 3];

    long long tid = (long long)blockIdx.x * 256 + threadIdx.x;
    long long stride = (long long)gridDim.x * 256;

    if (count <= CAND_CAP) {
        const unsigned* cand = ws + CAND_OFF;
        for (long long i = tid; i < (long long)count; i += stride) {
            unsigned idx = cand[i];
            float x = lg[idx];
            unsigned u = refine_A(x) | 1u;    // bit-identical to stored bits
            if (u >= glo && u < ghi) {
                unsigned eb = exact_bits(x);  // TRUE untagged bits
                unsigned rB = u;
                unsigned d = u & 16383u;
                if (d < medge || d >= 16384u - medge) rB = eb | 1u;
                if (rB >= wlo && rB < whi) {
                    unsigned off = eb - wlo;
                    if (off < 16384u) atomicAdd(&ws[HC_OFF + off], 1u);
                }
            }
        }
    } else {
        // overflow fallback: rescan full out array (never expected)
        long long n4 = n >> 2;
        const u32x4* o4 = (const u32x4*)ob;
        for (long long i = tid; i < n4; i += stride) {
            u32x4 u4 = o4[i];
            unsigned us[4] = {u4.x, u4.y, u4.z, u4.w};
#pragma unroll
            for (int c = 0; c < 4; ++c) {
                unsigned u = us[c];
                if ((u & 1u) && u != 1u && u >= glo && u < ghi) {
                    float x = lg[i * 4 + c];
                    unsigned eb = exact_bits(x);
                    unsigned rB = u;
                    unsigned d = u & 16383u;
                    if (d < medge || d >= 16384u - medge) rB = eb | 1u;
                    if (rB >= wlo && rB < whi) {
                        unsigned off = eb - wlo;
                        if (off < 16384u) atomicAdd(&ws[HC_OFF + off], 1u);
                    }
                }
            }
        }
        if (tid == 0) {
            for (long long q = (n4 << 2); q < n; ++q) {
                unsigned u = ob[q];
                if ((u & 1u) && u != 1u && u >= glo && u < ghi) {
                    unsigned eb = exact_bits(lg[q]);
                    unsigned rB = u;
                    unsigned d = u & 16383u;
                    if (d < medge || d >= 16384u - medge) rB = eb | 1u;
                    if (rB >= wlo && rB < whi) {
                        unsigned off = eb - wlo;
                        if (off < 16384u) atomicAdd(&ws[HC_OFF + off], 1u);
                    }
                }
            }
        }
    }
}

// --- k6: exact threshold bits from histC ----------------------------------
__global__ __launch_bounds__(1024) void k6_selwin(unsigned* __restrict__ ws) {
    unsigned* ctrl = ws + CTRL_OFF;
    if (ctrl[4] == 0xFFFFFFFFu) return;
    __shared__ unsigned long long csum[1024];
    int t = threadIdx.x;
    unsigned long long s = 0;
    for (int j = 0; j < 16; ++j) s += ws[HC_OFF + t * 16 + j];
    csum[t] = s;
    __syncthreads();
    if (t == 0) {
        long long kpp = (long long)ctrl[5];
        long long cum = 0;
        int sel = 0;
        long long rem = kpp;
        for (int c = 1023; c >= 0; --c) {
            if (cum + (long long)csum[c] >= kpp) {
                sel = c;
                rem = kpp - cum;
                break;
            }
            cum += csum[c];
        }
        long long cc = 0;
        int bsel = 0;
        for (int j = 15; j >= 0; --j) {
            unsigned v = ws[HC_OFF + sel * 16 + j];
            if (cc + (long long)v >= rem) {
                bsel = j;
                break;
            }
            cc += v;
        }
        ctrl[2] = ctrl[4] + (unsigned)(sel * 16 + bsel);
    }
}

// --- kD_cand: fixup ONLY the candidates (main path) ------------------------
__global__ __launch_bounds__(256) void kD_cand(
    const float* __restrict__ lg, unsigned* __restrict__ ob,
    const unsigned* __restrict__ ws) {
    unsigned count = ws[CTRL_OFF + 3];
    if (count > CAND_CAP) return;           // fallback kernel handles it
    unsigned thr = ws[CTRL_OFF + 2];
    unsigned mband = ws[CTRL_OFF + 6] + 2u;
    const unsigned* cand = ws + CAND_OFF;

    long long tid = (long long)blockIdx.x * 256 + threadIdx.x;
    long long stride = (long long)gridDim.x * 256;
    for (long long i = tid; i < (long long)count; i += stride) {
        unsigned idx = cand[i];
        unsigned u = ob[idx];
        unsigned udiff = (u > thr) ? u - thr : thr - u;
        if (udiff <= mband) {               // banded: exact decision
            unsigned eb = exact_bits(lg[idx]);
            if (eb > thr) ob[idx] = 0u;
        } else if (u > thr) {
            ob[idx] = 0u;                   // rejected
        }
        // kept: tagged value stays (<=2 ulp off true loss, bf16 absorbs)
    }
}

// --- kD_full: fallback full-array rewrite (cand overflow only) -------------
__device__ __forceinline__ unsigned kD_elem(unsigned u, unsigned thr,
                                            unsigned mband,
                                            const float* __restrict__ lg,
                                            long long idx, bool* changed) {
    if (!(u & 1u)) return u;                        // known/zero: final
    unsigned udiff = (u > thr) ? u - thr : thr - u;
    if (udiff <= mband) {
        unsigned eb = exact_bits(lg[idx]);
        unsigned r = (eb > thr) ? 0u : eb;
        *changed |= (r != u);
        return r;
    }
    if (u > thr) { *changed = true; return 0u; }
    return u;
}

__global__ __launch_bounds__(256) void kD_full(
    const float* __restrict__ lg, unsigned* __restrict__ ob,
    const unsigned* __restrict__ ws, long long n) {
    if (ws[CTRL_OFF + 3] <= CAND_CAP) return;       // main path handled it
    unsigned thr = ws[CTRL_OFF + 2];
    unsigned mband = ws[CTRL_OFF + 6] + 2u;

    long long n8 = n >> 3;
    long long tid = (long long)blockIdx.x * 256 + threadIdx.x;
    long long stride = (long long)gridDim.x * 256;
    u32x4* o4 = (u32x4*)ob;

    for (long long i = tid; i < n8; i += stride) {
        u32x4 ua = o4[2 * i];
        u32x4 ub = o4[2 * i + 1];
        u32x4 va, vb;
        bool chA = false, chB = false;
        long long base = i * 8;
        va.x = kD_elem(ua.x, thr, mband, lg, base + 0, &chA);
        va.y = kD_elem(ua.y, thr, mband, lg, base + 1, &chA);
        va.z = kD_elem(ua.z, thr, mband, lg, base + 2, &chA);
        va.w = kD_elem(ua.w, thr, mband, lg, base + 3, &chA);
        vb.x = kD_elem(ub.x, thr, mband, lg, base + 4, &chB);
        vb.y = kD_elem(ub.y, thr, mband, lg, base + 5, &chB);
        vb.z = kD_elem(ub.z, thr, mband, lg, base + 6, &chB);
        vb.w = kD_elem(ub.w, thr, mband, lg, base + 7, &chB);
        if (chA) o4[2 * i] = va;
        if (chB) o4[2 * i + 1] = vb;
    }
    if (tid == 0) {
        for (long long q = (n >> 3) << 3; q < n; ++q) {
            bool ch = false;
            unsigned r = kD_elem(ob[q], thr, mband, lg, q, &ch);
            if (ch) ob[q] = r;
        }
    }
}

extern "C" void kernel_launch(void* const* d_in, const int* in_sizes, int n_in,
                              void* d_out, int out_size, void* d_ws, size_t ws_size,
                              hipStream_t stream) {
    const float* lg = (const float*)d_in[0];
    const float* tg = (const float*)d_in[1];
    const int* epoch = (const int*)d_in[2];
    float* out = (float*)d_out;
    unsigned* ob = (unsigned*)d_out;
    unsigned* ws = (unsigned*)d_ws;
    long long n = (long long)in_sizes[0];

    (void)hipMemsetAsync(d_ws, 0, (size_t)ZERO_WORDS * 4, stream);

    const int blocks = 2048, threads = 256;
    kA_store_hist<<<blocks, threads, 0, stream>>>(lg, tg, out, ws, n);
    k2_sel12<<<1, 256, 0, stream>>>(ws, epoch);
    kB_zero<<<blocks, threads, 0, stream>>>(lg, ob, ws, n);
    k4_sel64<<<1, 64, 0, stream>>>(ws);
    kC_histwin<<<1024, threads, 0, stream>>>(lg, ob, ws, n);
    k6_selwin<<<1, 1024, 0, stream>>>(ws);
    kD_cand<<<256, threads, 0, stream>>>(lg, ob, ws);
    kD_full<<<blocks, threads, 0, stream>>>(lg, ob, ws, n);
}